// Round 1
// baseline (4399.780 us; speedup 1.0000x reference)
//
#include <hip/hip_runtime.h>

// Qwen3-style decoder, 28 layers, Q=512, D=1024, HQ=16, HKV=8, HD=128, DFF=3072.
// Strategy: bf16 MFMA GEMMs (weights converted fp32->bf16 while staging to LDS),
// f16 MFMA flash attention (matches reference's fp16 cast of K/V), fp32 residual
// stream in workspace. Split-K GEMMs write partials; reduction fused into the
// following rmsnorm kernel. Workspace use ~41MB.

typedef __bf16 bf16_t;
typedef _Float16 f16_t;
typedef __bf16 bf16x8 __attribute__((ext_vector_type(8)));
typedef __bf16 bf16x4 __attribute__((ext_vector_type(4)));
typedef _Float16 f16x8 __attribute__((ext_vector_type(8)));
typedef _Float16 f16x4 __attribute__((ext_vector_type(4)));
typedef float f32x4 __attribute__((ext_vector_type(4)));

#define SEQ 512
#define DMODEL 1024
#define NHQ 16
#define NHKV 8
#define HD 128

// ---------------------------------------------------------------------------
// residual-add (optional split-K partials) + RMSNorm -> bf16 out
// one block per token row (1024 elems, 256 threads x float4)
__global__ __launch_bounds__(256) void k_resid_rms(
    float* __restrict__ h, const float* __restrict__ parts, int nparts,
    const float* __restrict__ w, bf16_t* __restrict__ xout)
{
    int t = blockIdx.x, tid = threadIdx.x;
    size_t base = (size_t)t * 1024 + tid * 4;
    float4 v = *(const float4*)(h + base);
    for (int p = 0; p < nparts; ++p) {
        float4 a = *(const float4*)(parts + (size_t)p * 524288 + base);
        v.x += a.x; v.y += a.y; v.z += a.z; v.w += a.w;
    }
    if (nparts) *(float4*)(h + base) = v;
    float ss = v.x * v.x + v.y * v.y + v.z * v.z + v.w * v.w;
#pragma unroll
    for (int m = 1; m < 64; m <<= 1) ss += __shfl_xor(ss, m);
    __shared__ float red[4];
    if ((tid & 63) == 0) red[tid >> 6] = ss;
    __syncthreads();
    float tot = (red[0] + red[1]) + (red[2] + red[3]);
    float sc = rsqrtf(tot * (1.0f / 1024.0f) + 1e-6f);
    float4 wv4 = *(const float4*)(w + tid * 4);
    bf16x4 o;
    o[0] = (bf16_t)(v.x * sc * wv4.x);
    o[1] = (bf16_t)(v.y * sc * wv4.y);
    o[2] = (bf16_t)(v.z * sc * wv4.z);
    o[3] = (bf16_t)(v.w * sc * wv4.w);
    *(bf16x4*)(xout + base) = o;
}

// ---------------------------------------------------------------------------
// final: out = h + sum(4 partials)   (fp32 out)
__global__ __launch_bounds__(256) void k_finalize(
    const float* __restrict__ h, const float* __restrict__ parts,
    float* __restrict__ out)
{
    size_t base = ((size_t)blockIdx.x * 256 + threadIdx.x) * 4;
    float4 v = *(const float4*)(h + base);
#pragma unroll
    for (int p = 0; p < 4; ++p) {
        float4 a = *(const float4*)(parts + (size_t)p * 524288 + base);
        v.x += a.x; v.y += a.y; v.z += a.z; v.w += a.w;
    }
    *(float4*)(out + base) = v;
}

// ---------------------------------------------------------------------------
// GEMM: C[M=512,N] = A(bf16, MxK) @ B(fp32, KxN, selected from up to 3 weights)
// BM=64 BN=128 BK=64, 256 threads (4 waves, each 64x32 via 16x16x32 bf16 MFMA).
// B converted to bf16 and stored transposed in LDS so both fragment reads are
// contiguous ds_read_b128. Register double-buffered global loads.
// Swizzled blockIdx so the 8 WGs sharing a (bn,s) B-panel land on one XCD.
// SPLITK>1: each s-chunk stores to C + s*spart (plain store).
#define GBM 64
#define GBN 128
#define GBK 64
#define GMB 8   // 512/64

template <int SPLITK>
__global__ __launch_bounds__(256) void gemm_k(
    const bf16_t* __restrict__ A, int lda,
    const float* __restrict__ B0, int nc0,
    const float* __restrict__ B1, int nc1,
    const float* __restrict__ B2,
    float* __restrict__ C, int ldc, size_t spart, int K)
{
    int f = blockIdx.x;
    int xc = f & 7;
    int tt = f >> 3;
    int bm = tt % GMB;
    int g = xc + 8 * (tt / GMB);
    int bn = g / SPLITK;
    int s = g % SPLITK;
    const int Kc = K / SPLITK;
    int k0base = s * Kc;

    __shared__ bf16_t As[GBM][GBK + 8];   // 64 x 72
    __shared__ bf16_t Bs[GBN][GBK + 8];   // 128 x 72 (transposed: [n][k])

    int tid = threadIdx.x;
    int wv = tid >> 6, l = tid & 63, lg = l >> 4, lr = l & 15;

    int n_base = bn * GBN;
    const float* B; int ldb, ncol;
    if (n_base < nc0)            { B = B0; ldb = nc0; ncol = n_base; }
    else if (n_base < nc0 + nc1) { B = B1; ldb = nc1; ncol = n_base - nc0; }
    else                         { B = B2; ldb = nc1; ncol = n_base - nc0 - nc1; }

    int ar = tid >> 3, aseg = tid & 7;    // A staging: rows ar, ar+32
    int nq = tid & 31, kb = tid >> 5;     // B staging: n=nq*4, k=kb*4 (+p*32)

    const bf16_t* Ap0 = A + (size_t)(bm * GBM + ar) * lda + aseg * 8;
    const bf16_t* Ap1 = Ap0 + (size_t)32 * lda;
    const float* Bp = B + (size_t)ncol + nq * 4;

    int4 aR[2];
    float4 bR[8];
    auto load_tile = [&](int kt) {
        int k0 = k0base + kt * GBK;
        aR[0] = *(const int4*)(Ap0 + k0);
        aR[1] = *(const int4*)(Ap1 + k0);
        const float* bp = Bp + (size_t)(k0 + kb * 4) * ldb;
#pragma unroll
        for (int p = 0; p < 2; ++p)
#pragma unroll
            for (int r = 0; r < 4; ++r)
                bR[p * 4 + r] = *(const float4*)(bp + (size_t)(p * 32 + r) * ldb);
    };

    f32x4 acc[4][2];
#pragma unroll
    for (int i = 0; i < 4; ++i)
#pragma unroll
        for (int j = 0; j < 2; ++j) { f32x4 z = {0.f, 0.f, 0.f, 0.f}; acc[i][j] = z; }

    int niter = Kc / GBK;
    load_tile(0);
    for (int kt = 0; kt < niter; ++kt) {
        __syncthreads();
        *(int4*)&As[ar][aseg * 8] = aR[0];
        *(int4*)&As[ar + 32][aseg * 8] = aR[1];
#pragma unroll
        for (int p = 0; p < 2; ++p) {
            float* f0 = (float*)&bR[p * 4 + 0];
            float* f1 = (float*)&bR[p * 4 + 1];
            float* f2 = (float*)&bR[p * 4 + 2];
            float* f3 = (float*)&bR[p * 4 + 3];
#pragma unroll
            for (int nn = 0; nn < 4; ++nn) {
                bf16x4 pk;
                pk[0] = (bf16_t)f0[nn];
                pk[1] = (bf16_t)f1[nn];
                pk[2] = (bf16_t)f2[nn];
                pk[3] = (bf16_t)f3[nn];
                *(bf16x4*)&Bs[nq * 4 + nn][p * 32 + kb * 4] = pk;
            }
        }
        __syncthreads();
        if (kt + 1 < niter) load_tile(kt + 1);
#pragma unroll
        for (int c = 0; c < 2; ++c) {
            bf16x8 af[4], bfr[2];
#pragma unroll
            for (int i = 0; i < 4; ++i)
                af[i] = *(const bf16x8*)&As[i * 16 + lr][c * 32 + lg * 8];
#pragma unroll
            for (int j = 0; j < 2; ++j)
                bfr[j] = *(const bf16x8*)&Bs[wv * 32 + j * 16 + lr][c * 32 + lg * 8];
#pragma unroll
            for (int i = 0; i < 4; ++i)
#pragma unroll
                for (int j = 0; j < 2; ++j)
                    acc[i][j] = __builtin_amdgcn_mfma_f32_16x16x32_bf16(
                        af[i], bfr[j], acc[i][j], 0, 0, 0);
        }
    }
    float* Cw = C + (size_t)s * spart;
#pragma unroll
    for (int i = 0; i < 4; ++i)
#pragma unroll
        for (int j = 0; j < 2; ++j)
#pragma unroll
            for (int ii = 0; ii < 4; ++ii) {
                int m = bm * GBM + i * 16 + lg * 4 + ii;
                int n = n_base + wv * 32 + j * 16 + lr;
                Cw[(size_t)m * ldc + n] = acc[i][j][ii];
            }
}

// ---------------------------------------------------------------------------
// per-(token, head-slot) RMSNorm (q/k) + RoPE, write fp16 q/k
// slots 0..15 = q heads, 16..23 = k heads. 128 threads = one d each.
__global__ __launch_bounds__(128) void k_qknorm_rope(
    const float* __restrict__ qkv,
    const float* __restrict__ qw, const float* __restrict__ kw,
    const float* __restrict__ cosb, const float* __restrict__ sinb,
    f16_t* __restrict__ qf, f16_t* __restrict__ kf)
{
    int slot = blockIdx.x % 24;
    int t = blockIdx.x / 24;
    int d = threadIdx.x;
    bool isq = slot < 16;
    int col = isq ? slot * HD + d : 2048 + (slot - 16) * HD + d;
    float x = qkv[(size_t)t * 4096 + col];
    float ss = x * x;
#pragma unroll
    for (int m = 1; m < 64; m <<= 1) ss += __shfl_xor(ss, m);
    __shared__ float red[2];
    __shared__ float xs[128];
    if ((d & 63) == 0) red[d >> 6] = ss;
    __syncthreads();
    float tot = red[0] + red[1];
    float sc = rsqrtf(tot * (1.0f / 128.0f) + 1e-6f);
    float xn = x * sc * (isq ? qw[d] : kw[d]);
    xs[d] = xn;
    __syncthreads();
    float part = xs[d ^ 64];
    float rot = (d < 64) ? -part : part;
    float o = xn * cosb[t * HD + d] + rot * sinb[t * HD + d];
    f16_t of = (f16_t)o;
    if (isq) qf[((size_t)slot * SEQ + t) * HD + d] = of;
    else     kf[((size_t)(slot - 16) * SEQ + t) * HD + d] = of;
}

// ---------------------------------------------------------------------------
// V transpose: qkv v-part fp32 [t][kvh*128+d] -> vT fp16 [kvh][d][t]
// block = (kvh, 128-token tile), 256 threads
__global__ __launch_bounds__(256) void k_vtrans(
    const float* __restrict__ qkv, f16_t* __restrict__ vT)
{
    int kvh = blockIdx.x >> 2, tb = blockIdx.x & 3;
    __shared__ f16_t tileS[128][136];
    int tid = threadIdx.x;
#pragma unroll
    for (int it = 0; it < 16; ++it) {
        int r = it * 8 + (tid >> 5);
        int cs = tid & 31;
        float4 v = *(const float4*)(qkv + (size_t)(tb * 128 + r) * 4096 + 3072 + kvh * HD + cs * 4);
        f16x4 o;
        o[0] = (f16_t)v.x; o[1] = (f16_t)v.y; o[2] = (f16_t)v.z; o[3] = (f16_t)v.w;
        *(f16x4*)&tileS[r][cs * 4] = o;
    }
    __syncthreads();
#pragma unroll
    for (int it = 0; it < 8; ++it) {
        int dr = it * 16 + (tid >> 4);
        int seg = tid & 15;
        f16x8 o;
#pragma unroll
        for (int j = 0; j < 8; ++j) o[j] = tileS[seg * 8 + j][dr];
        *(f16x8*)(vT + ((size_t)kvh * HD + dr) * SEQ + tb * 128 + seg * 8) = o;
    }
}

// ---------------------------------------------------------------------------
// causal flash attention, f16 MFMA, online softmax.
// block = (head, 32-q-row tile), 2 waves x 16 q-rows. K-tiles of 64.
__global__ __launch_bounds__(128) void k_attn(
    const f16_t* __restrict__ qf, const f16_t* __restrict__ kf,
    const f16_t* __restrict__ vT, bf16_t* __restrict__ out)
{
    int h = blockIdx.x >> 4, qb = blockIdx.x & 15;
    int kvh = h >> 1;
    __shared__ f16_t Kt[64][136];        // [kt][d]
    __shared__ f16_t Vt[128][72];        // [d][kt]
    __shared__ f16_t Pl[2][16][72];      // per-wave P bounce [q][kt]
    int tid = threadIdx.x;
    int wv = tid >> 6, l = tid & 63, lg = l >> 4, lr = l & 15;
    int q0 = qb * 32;
    int qrow = q0 + wv * 16;

    f16x8 aq[4];
    const f16_t* qp = qf + ((size_t)h * SEQ + qrow + lr) * HD;
#pragma unroll
    for (int c = 0; c < 4; ++c) aq[c] = *(const f16x8*)(qp + c * 32 + lg * 8);

    f32x4 accv[8];
#pragma unroll
    for (int df = 0; df < 8; ++df) { f32x4 z = {0.f, 0.f, 0.f, 0.f}; accv[df] = z; }
    float mrun[4], lrun[4];
#pragma unroll
    for (int ii = 0; ii < 4; ++ii) { mrun[ii] = -3e38f; lrun[ii] = 0.f; }

    int ktiles = (q0 + 32 + 63) >> 6;
    for (int kt = 0; kt < ktiles; ++kt) {
        int kt0 = kt * 64;
        __syncthreads();
#pragma unroll
        for (int it = 0; it < 8; ++it) {
            int idx = it * 128 + tid;
            int r = idx >> 4, seg = idx & 15;
            *(int4*)&Kt[r][seg * 8] =
                *(const int4*)(kf + ((size_t)kvh * SEQ + kt0 + r) * HD + seg * 8);
        }
#pragma unroll
        for (int it = 0; it < 8; ++it) {
            int idx = it * 128 + tid;
            int r = idx >> 3, seg = idx & 7;
            *(int4*)&Vt[r][seg * 8] =
                *(const int4*)(vT + ((size_t)kvh * HD + r) * SEQ + kt0 + seg * 8);
        }
        __syncthreads();

        f32x4 s[4];
#pragma unroll
        for (int nf = 0; nf < 4; ++nf) {
            f32x4 a = {0.f, 0.f, 0.f, 0.f};
#pragma unroll
            for (int c = 0; c < 4; ++c) {
                f16x8 bk = *(const f16x8*)&Kt[nf * 16 + lr][c * 32 + lg * 8];
                a = __builtin_amdgcn_mfma_f32_16x16x32_f16(aq[c], bk, a, 0, 0, 0);
            }
            s[nf] = a;
        }
        const float scale = 0.08838834764831845f;
        float tmax[4] = {-3e38f, -3e38f, -3e38f, -3e38f};
#pragma unroll
        for (int nf = 0; nf < 4; ++nf) {
            int ktg = kt0 + nf * 16 + lr;
#pragma unroll
            for (int ii = 0; ii < 4; ++ii) {
                int qg = qrow + lg * 4 + ii;
                float vv = s[nf][ii] * scale;
                vv = (ktg <= qg) ? vv : -1e30f;
                s[nf][ii] = vv;
                tmax[ii] = fmaxf(tmax[ii], vv);
            }
        }
#pragma unroll
        for (int m = 1; m < 16; m <<= 1)
#pragma unroll
            for (int ii = 0; ii < 4; ++ii)
                tmax[ii] = fmaxf(tmax[ii], __shfl_xor(tmax[ii], m));
        float corr[4];
#pragma unroll
        for (int ii = 0; ii < 4; ++ii) {
            float mnew = fmaxf(mrun[ii], tmax[ii]);
            corr[ii] = __expf(mrun[ii] - mnew);
            mrun[ii] = mnew;
        }
        float tsum[4] = {0.f, 0.f, 0.f, 0.f};
#pragma unroll
        for (int nf = 0; nf < 4; ++nf)
#pragma unroll
            for (int ii = 0; ii < 4; ++ii) {
                float pp = __expf(s[nf][ii] - mrun[ii]);
                s[nf][ii] = pp;
                tsum[ii] += pp;
            }
#pragma unroll
        for (int m = 1; m < 16; m <<= 1)
#pragma unroll
            for (int ii = 0; ii < 4; ++ii) tsum[ii] += __shfl_xor(tsum[ii], m);
#pragma unroll
        for (int ii = 0; ii < 4; ++ii) lrun[ii] = lrun[ii] * corr[ii] + tsum[ii];
#pragma unroll
        for (int df = 0; df < 8; ++df)
#pragma unroll
            for (int ii = 0; ii < 4; ++ii) accv[df][ii] *= corr[ii];
#pragma unroll
        for (int nf = 0; nf < 4; ++nf)
#pragma unroll
            for (int ii = 0; ii < 4; ++ii)
                Pl[wv][lg * 4 + ii][nf * 16 + lr] = (f16_t)s[nf][ii];
        __syncthreads();
#pragma unroll
        for (int c = 0; c < 2; ++c) {
            f16x8 ap = *(const f16x8*)&Pl[wv][lr][c * 32 + lg * 8];
#pragma unroll
            for (int df = 0; df < 8; ++df) {
                f16x8 bv = *(const f16x8*)&Vt[df * 16 + lr][c * 32 + lg * 8];
                accv[df] = __builtin_amdgcn_mfma_f32_16x16x32_f16(ap, bv, accv[df], 0, 0, 0);
            }
        }
    }
#pragma unroll
    for (int df = 0; df < 8; ++df)
#pragma unroll
        for (int ii = 0; ii < 4; ++ii) {
            int qg = qrow + lg * 4 + ii;
            out[(size_t)qg * 2048 + h * HD + df * 16 + lr] =
                (bf16_t)(accv[df][ii] / lrun[ii]);
        }
}

// ---------------------------------------------------------------------------
// swiglu: m = silu(g) * u, gu = [512][6144] fp32 -> mbuf [512][3072] bf16
__global__ __launch_bounds__(256) void k_swiglu(
    const float* __restrict__ gu, bf16_t* __restrict__ mout)
{
    int idx = blockIdx.x * 256 + threadIdx.x;
    int t = idx / 768, c = idx % 768;
    const float* row = gu + (size_t)t * 6144;
    float4 g = *(const float4*)(row + c * 4);
    float4 u = *(const float4*)(row + 3072 + c * 4);
    bf16x4 o;
    o[0] = (bf16_t)(g.x / (1.f + __expf(-g.x)) * u.x);
    o[1] = (bf16_t)(g.y / (1.f + __expf(-g.y)) * u.y);
    o[2] = (bf16_t)(g.z / (1.f + __expf(-g.z)) * u.z);
    o[3] = (bf16_t)(g.w / (1.f + __expf(-g.w)) * u.w);
    *(bf16x4*)(mout + (size_t)t * 3072 + c * 4) = o;
}

// ---------------------------------------------------------------------------
extern "C" void kernel_launch(void* const* d_in, const int* in_sizes, int n_in,
                              void* d_out, int out_size, void* d_ws, size_t ws_size,
                              hipStream_t stream)
{
    const float* hin  = (const float*)d_in[0];
    const float* cosb = (const float*)d_in[1];
    const float* sinb = (const float*)d_in[2];
    const float* Wq = (const float*)d_in[4];
    const float* Wk = (const float*)d_in[5];
    const float* Wv = (const float*)d_in[6];
    const float* Wo = (const float*)d_in[7];
    const float* Wg = (const float*)d_in[8];
    const float* Wu = (const float*)d_in[9];
    const float* Wd = (const float*)d_in[10];
    const float* Ln1 = (const float*)d_in[11];
    const float* Ln2 = (const float*)d_in[12];
    const float* Qn = (const float*)d_in[13];
    const float* Kn = (const float*)d_in[14];

    char* p = (char*)d_ws;
    auto alloc = [&](size_t bytes) { char* r = p; p += bytes; return r; };
    float* h     = (float*)alloc((size_t)SEQ * 1024 * 4);         // 2MB
    float* qkv   = (float*)alloc((size_t)SEQ * 4096 * 4);         // 8MB
    float* gu    = (float*)alloc((size_t)SEQ * 6144 * 4);         // 12MB
    float* parts = (float*)alloc((size_t)4 * SEQ * 1024 * 4);     // 8MB
    bf16_t* x     = (bf16_t*)alloc((size_t)SEQ * 1024 * 2);       // 1MB
    bf16_t* y     = (bf16_t*)alloc((size_t)SEQ * 1024 * 2);       // 1MB
    bf16_t* attnb = (bf16_t*)alloc((size_t)SEQ * 2048 * 2);       // 2MB
    bf16_t* mbuf  = (bf16_t*)alloc((size_t)SEQ * 3072 * 2);       // 3MB
    f16_t* qf = (f16_t*)alloc((size_t)NHQ * SEQ * HD * 2);        // 2MB
    f16_t* kf = (f16_t*)alloc((size_t)NHKV * SEQ * HD * 2);       // 1MB
    f16_t* vT = (f16_t*)alloc((size_t)NHKV * HD * SEQ * 2);       // 1MB

    hipMemcpyAsync(h, hin, (size_t)SEQ * 1024 * 4, hipMemcpyDeviceToDevice, stream);

    for (int l = 0; l < 28; ++l) {
        const float* wq = Wq + (size_t)l * 1024 * 2048;
        const float* wk = Wk + (size_t)l * 1024 * 1024;
        const float* wv = Wv + (size_t)l * 1024 * 1024;
        const float* wo = Wo + (size_t)l * 2048 * 1024;
        const float* wg = Wg + (size_t)l * 1024 * 3072;
        const float* wu = Wu + (size_t)l * 1024 * 3072;
        const float* wd = Wd + (size_t)l * 3072 * 1024;

        // x = rmsnorm(h [+ prev mlp partials], ln1)
        k_resid_rms<<<512, 256, 0, stream>>>(h, parts, l == 0 ? 0 : 4,
                                             Ln1 + (size_t)l * 1024, x);
        // qkv = x @ [Wq|Wk|Wv]
        gemm_k<1><<<256, 256, 0, stream>>>(x, 1024, wq, 2048, wk, 1024, wv,
                                           qkv, 4096, (size_t)0, 1024);
        // q/k norm + rope -> fp16; v -> fp16 transposed
        k_qknorm_rope<<<512 * 24, 128, 0, stream>>>(qkv, Qn + (size_t)l * 128,
                                                    Kn + (size_t)l * 128,
                                                    cosb, sinb, qf, kf);
        k_vtrans<<<32, 256, 0, stream>>>(qkv, vT);
        // attention
        k_attn<<<256, 128, 0, stream>>>(qf, kf, vT, attnb);
        // attn @ Wo -> 4 partials (split-K)
        gemm_k<4><<<256, 256, 0, stream>>>(attnb, 2048, wo, 1024, nullptr, 0,
                                           nullptr, parts, 1024,
                                           (size_t)SEQ * 1024, 2048);
        // h += partials; y = rmsnorm(h, ln2)
        k_resid_rms<<<512, 256, 0, stream>>>(h, parts, 4,
                                             Ln2 + (size_t)l * 1024, y);
        // gu = y @ [Wg|Wu]
        gemm_k<1><<<384, 256, 0, stream>>>(y, 1024, wg, 3072, wu, 3072, nullptr,
                                           gu, 6144, (size_t)0, 1024);
        // m = silu(g)*u
        k_swiglu<<<1536, 256, 0, stream>>>(gu, mbuf);
        // m @ Wd -> 4 partials (consumed by next layer's k_resid_rms / finalize)
        gemm_k<4><<<256, 256, 0, stream>>>(mbuf, 3072, wd, 1024, nullptr, 0,
                                           nullptr, parts, 1024,
                                           (size_t)SEQ * 1024, 3072);
    }
    k_finalize<<<512, 256, 0, stream>>>(h, parts, (float*)d_out);
}

// Round 2
// 4038.752 us; speedup vs baseline: 1.0894x; 1.0894x over previous
//
#include <hip/hip_runtime.h>

// Qwen3-style decoder, 28 layers, Q=512, D=1024, HQ=16, HKV=8, HD=128, DFF=3072.
// R2: 64x64x64 GEMM tiles (2 blocks/CU), Bs pad+4, fused SwiGLU epilogue,
// f16 qkv output, wave-per-slot qknorm+rope.

typedef __bf16 bf16_t;
typedef _Float16 f16_t;
typedef __bf16 bf16x8 __attribute__((ext_vector_type(8)));
typedef __bf16 bf16x4 __attribute__((ext_vector_type(4)));
typedef _Float16 f16x8 __attribute__((ext_vector_type(8)));
typedef _Float16 f16x4 __attribute__((ext_vector_type(4)));
typedef float f32x4 __attribute__((ext_vector_type(4)));

#define SEQ 512
#define NHQ 16
#define NHKV 8
#define HD 128

// ---------------------------------------------------------------------------
// residual-add (optional split-K partials) + RMSNorm -> bf16 out
__global__ __launch_bounds__(256) void k_resid_rms(
    float* __restrict__ h, const float* __restrict__ parts, int nparts,
    const float* __restrict__ w, bf16_t* __restrict__ xout)
{
    int t = blockIdx.x, tid = threadIdx.x;
    size_t base = (size_t)t * 1024 + tid * 4;
    float4 v = *(const float4*)(h + base);
    for (int p = 0; p < nparts; ++p) {
        float4 a = *(const float4*)(parts + (size_t)p * 524288 + base);
        v.x += a.x; v.y += a.y; v.z += a.z; v.w += a.w;
    }
    if (nparts) *(float4*)(h + base) = v;
    float ss = v.x * v.x + v.y * v.y + v.z * v.z + v.w * v.w;
#pragma unroll
    for (int m = 1; m < 64; m <<= 1) ss += __shfl_xor(ss, m);
    __shared__ float red[4];
    if ((tid & 63) == 0) red[tid >> 6] = ss;
    __syncthreads();
    float tot = (red[0] + red[1]) + (red[2] + red[3]);
    float sc = rsqrtf(tot * (1.0f / 1024.0f) + 1e-6f);
    float4 wv4 = *(const float4*)(w + tid * 4);
    bf16x4 o;
    o[0] = (bf16_t)(v.x * sc * wv4.x);
    o[1] = (bf16_t)(v.y * sc * wv4.y);
    o[2] = (bf16_t)(v.z * sc * wv4.z);
    o[3] = (bf16_t)(v.w * sc * wv4.w);
    *(bf16x4*)(xout + base) = o;
}

// ---------------------------------------------------------------------------
__global__ __launch_bounds__(256) void k_finalize(
    const float* __restrict__ h, const float* __restrict__ parts,
    float* __restrict__ out)
{
    size_t base = ((size_t)blockIdx.x * 256 + threadIdx.x) * 4;
    float4 v = *(const float4*)(h + base);
#pragma unroll
    for (int p = 0; p < 4; ++p) {
        float4 a = *(const float4*)(parts + (size_t)p * 524288 + base);
        v.x += a.x; v.y += a.y; v.z += a.z; v.w += a.w;
    }
    *(float4*)(out + base) = v;
}

// ---------------------------------------------------------------------------
// GEMM: C[512,N] = A(bf16) @ B(fp32 K x N).  BM=BN=BK=64, 256 thr (2x2 waves,
// each 32x32).  MODE 0: fp32 out (split-K partials). MODE 1: paired Wg/Wu
// columns + fused silu(g)*u -> bf16. MODE 2: f16 out.
template <int SPLITK, int MODE>
__global__ __launch_bounds__(256) void gemm_k(
    const bf16_t* __restrict__ A, int lda,
    const float* __restrict__ B0, int nc0,
    const float* __restrict__ B1, int nc1,
    const float* __restrict__ B2,
    void* __restrict__ Cv, int ldc, size_t spart, int K)
{
    int f = blockIdx.x;
    int xc = f & 7, tt = f >> 3;
    int bm = tt & 7;
    int g = xc + 8 * (tt >> 3);          // same-g blocks share an XCD
    int bn = g / SPLITK, s = g % SPLITK;
    const int Kc = K / SPLITK;
    const int k0base = s * Kc;

    __shared__ bf16_t As[64][72];
    __shared__ bf16_t Bs[64][68];

    int tid = threadIdx.x;
    int wv = tid >> 6, l = tid & 63, lg = l >> 4, lr = l & 15;
    int wr = wv >> 1, wc = wv & 1;

    int arow = tid >> 3, aseg = tid & 7;   // A staging
    int c4 = tid & 15, r4 = tid >> 4;      // B staging

    const bf16_t* Ap = A + (size_t)(bm * 64 + arow) * lda + aseg * 8;

    const float* Bp; int ldb;
    if (MODE == 1) {
        ldb = nc1;
        int col = c4 * 4;
        Bp = (col < 32) ? (B0 + bn * 32 + col) : (B1 + bn * 32 + col - 32);
    } else {
        int n_base = bn * 64;
        const float* B; int ncol;
        if (n_base < nc0)            { B = B0; ldb = nc0; ncol = n_base; }
        else if (n_base < nc0 + nc1) { B = B1; ldb = nc1; ncol = n_base - nc0; }
        else                         { B = B2; ldb = nc1; ncol = n_base - nc0 - nc1; }
        Bp = B + ncol + c4 * 4;
    }

    int4 aR[2];
    float4 bR[4];
    auto load_tile = [&](int kt) {
        int k0 = k0base + kt * 64;
        aR[0] = *(const int4*)(Ap + k0);
        aR[1] = *(const int4*)(Ap + (size_t)32 * lda + k0);
        const float* bp = Bp + (size_t)(k0 + r4 * 4) * ldb;
#pragma unroll
        for (int i = 0; i < 4; ++i)
            bR[i] = *(const float4*)(bp + (size_t)i * ldb);
    };

    f32x4 acc[2][2];
#pragma unroll
    for (int i = 0; i < 2; ++i)
#pragma unroll
        for (int j = 0; j < 2; ++j) { f32x4 z = {0.f, 0.f, 0.f, 0.f}; acc[i][j] = z; }

    int niter = Kc / 64;
    load_tile(0);
    for (int kt = 0; kt < niter; ++kt) {
        __syncthreads();
        *(int4*)&As[arow][aseg * 8] = aR[0];
        *(int4*)&As[arow + 32][aseg * 8] = aR[1];
        {
            float* f0 = (float*)&bR[0];
            float* f1 = (float*)&bR[1];
            float* f2 = (float*)&bR[2];
            float* f3 = (float*)&bR[3];
#pragma unroll
            for (int nn = 0; nn < 4; ++nn) {
                bf16x4 pk;
                pk[0] = (bf16_t)f0[nn];
                pk[1] = (bf16_t)f1[nn];
                pk[2] = (bf16_t)f2[nn];
                pk[3] = (bf16_t)f3[nn];
                *(bf16x4*)&Bs[c4 * 4 + nn][r4 * 4] = pk;
            }
        }
        __syncthreads();
        if (kt + 1 < niter) load_tile(kt + 1);
#pragma unroll
        for (int c = 0; c < 2; ++c) {
            bf16x8 af[2], bfr[2];
            af[0] = *(const bf16x8*)&As[wr * 32 + lr][c * 32 + lg * 8];
            af[1] = *(const bf16x8*)&As[wr * 32 + 16 + lr][c * 32 + lg * 8];
            if (MODE == 1) {
                bfr[0] = *(const bf16x8*)&Bs[wc * 16 + lr][c * 32 + lg * 8];
                bfr[1] = *(const bf16x8*)&Bs[32 + wc * 16 + lr][c * 32 + lg * 8];
            } else {
                bfr[0] = *(const bf16x8*)&Bs[wc * 32 + lr][c * 32 + lg * 8];
                bfr[1] = *(const bf16x8*)&Bs[wc * 32 + 16 + lr][c * 32 + lg * 8];
            }
#pragma unroll
            for (int i = 0; i < 2; ++i)
#pragma unroll
                for (int j = 0; j < 2; ++j)
                    acc[i][j] = __builtin_amdgcn_mfma_f32_16x16x32_bf16(
                        af[i], bfr[j], acc[i][j], 0, 0, 0);
        }
    }

    if (MODE == 0) {
        float* Cw = (float*)Cv + (size_t)s * spart;
#pragma unroll
        for (int i = 0; i < 2; ++i)
#pragma unroll
            for (int j = 0; j < 2; ++j)
#pragma unroll
                for (int ii = 0; ii < 4; ++ii) {
                    int m = bm * 64 + wr * 32 + i * 16 + lg * 4 + ii;
                    int n = bn * 64 + wc * 32 + j * 16 + lr;
                    Cw[(size_t)m * ldc + n] = acc[i][j][ii];
                }
    } else if (MODE == 2) {
        f16_t* Cw = (f16_t*)Cv;
#pragma unroll
        for (int i = 0; i < 2; ++i)
#pragma unroll
            for (int j = 0; j < 2; ++j)
#pragma unroll
                for (int ii = 0; ii < 4; ++ii) {
                    int m = bm * 64 + wr * 32 + i * 16 + lg * 4 + ii;
                    int n = bn * 64 + wc * 32 + j * 16 + lr;
                    Cw[(size_t)m * ldc + n] = (f16_t)acc[i][j][ii];
                }
    } else {
        bf16_t* Cw = (bf16_t*)Cv;
        int col = bn * 32 + wc * 16 + lr;
#pragma unroll
        for (int i = 0; i < 2; ++i)
#pragma unroll
            for (int ii = 0; ii < 4; ++ii) {
                int m = bm * 64 + wr * 32 + i * 16 + lg * 4 + ii;
                float gv = acc[i][0][ii], uv = acc[i][1][ii];
                Cw[(size_t)m * ldc + col] = (bf16_t)(gv / (1.f + __expf(-gv)) * uv);
            }
    }
}

// ---------------------------------------------------------------------------
// q/k head RMSNorm + RoPE.  One wave per (token, slot); lane d handles the
// (d, d+64) rotate pair.  slots 0..15 = q heads, 16..23 = k heads.
__global__ __launch_bounds__(256) void k_qknr(
    const f16_t* __restrict__ qkvh,
    const float* __restrict__ qw, const float* __restrict__ kw,
    const float* __restrict__ cosb, const float* __restrict__ sinb,
    f16_t* __restrict__ qf, f16_t* __restrict__ kf)
{
    int tid = threadIdx.x;
    int idx = blockIdx.x * 4 + (tid >> 6);
    int slot = idx % 24;
    int t = idx / 24;
    int d = tid & 63;
    bool isq = slot < 16;
    int col = isq ? slot * HD + d : 2048 + (slot - 16) * HD + d;
    const f16_t* row = qkvh + (size_t)t * 4096;
    float x1 = (float)row[col];
    float x2 = (float)row[col + 64];
    float ss = x1 * x1 + x2 * x2;
#pragma unroll
    for (int m = 1; m < 64; m <<= 1) ss += __shfl_xor(ss, m);
    float sc = rsqrtf(ss * (1.0f / 128.0f) + 1e-6f);
    float w1 = isq ? qw[d] : kw[d];
    float w2 = isq ? qw[d + 64] : kw[d + 64];
    float xn1 = x1 * sc * w1, xn2 = x2 * sc * w2;
    float o1 = xn1 * cosb[t * HD + d] - xn2 * sinb[t * HD + d];
    float o2 = xn2 * cosb[t * HD + d + 64] + xn1 * sinb[t * HD + d + 64];
    if (isq) {
        f16_t* o = qf + ((size_t)slot * SEQ + t) * HD;
        o[d] = (f16_t)o1; o[d + 64] = (f16_t)o2;
    } else {
        f16_t* o = kf + ((size_t)(slot - 16) * SEQ + t) * HD;
        o[d] = (f16_t)o1; o[d + 64] = (f16_t)o2;
    }
}

// ---------------------------------------------------------------------------
// V transpose: qkv v-part f16 [t][kvh*128+d] -> vT f16 [kvh][d][t]
__global__ __launch_bounds__(256) void k_vtrans(
    const f16_t* __restrict__ qkvh, f16_t* __restrict__ vT)
{
    int kvh = blockIdx.x >> 2, tb = blockIdx.x & 3;
    __shared__ f16_t tileS[128][136];
    int tid = threadIdx.x;
#pragma unroll
    for (int it = 0; it < 8; ++it) {
        int r = it * 16 + (tid >> 4);
        int cs = tid & 15;
        f16x8 v = *(const f16x8*)(qkvh + (size_t)(tb * 128 + r) * 4096 + 3072 + kvh * HD + cs * 8);
        *(f16x8*)&tileS[r][cs * 8] = v;
    }
    __syncthreads();
#pragma unroll
    for (int it = 0; it < 8; ++it) {
        int dr = it * 16 + (tid >> 4);
        int seg = tid & 15;
        f16x8 o;
#pragma unroll
        for (int j = 0; j < 8; ++j) o[j] = tileS[seg * 8 + j][dr];
        *(f16x8*)(vT + ((size_t)kvh * HD + dr) * SEQ + tb * 128 + seg * 8) = o;
    }
}

// ---------------------------------------------------------------------------
// causal flash attention, f16 MFMA, online softmax. (unchanged from R1)
__global__ __launch_bounds__(128) void k_attn(
    const f16_t* __restrict__ qf, const f16_t* __restrict__ kf,
    const f16_t* __restrict__ vT, bf16_t* __restrict__ out)
{
    int h = blockIdx.x >> 4, qb = blockIdx.x & 15;
    int kvh = h >> 1;
    __shared__ f16_t Kt[64][136];
    __shared__ f16_t Vt[128][72];
    __shared__ f16_t Pl[2][16][72];
    int tid = threadIdx.x;
    int wv = tid >> 6, l = tid & 63, lg = l >> 4, lr = l & 15;
    int q0 = qb * 32;
    int qrow = q0 + wv * 16;

    f16x8 aq[4];
    const f16_t* qp = qf + ((size_t)h * SEQ + qrow + lr) * HD;
#pragma unroll
    for (int c = 0; c < 4; ++c) aq[c] = *(const f16x8*)(qp + c * 32 + lg * 8);

    f32x4 accv[8];
#pragma unroll
    for (int df = 0; df < 8; ++df) { f32x4 z = {0.f, 0.f, 0.f, 0.f}; accv[df] = z; }
    float mrun[4], lrun[4];
#pragma unroll
    for (int ii = 0; ii < 4; ++ii) { mrun[ii] = -3e38f; lrun[ii] = 0.f; }

    int ktiles = (q0 + 32 + 63) >> 6;
    for (int kt = 0; kt < ktiles; ++kt) {
        int kt0 = kt * 64;
        __syncthreads();
#pragma unroll
        for (int it = 0; it < 8; ++it) {
            int idx = it * 128 + tid;
            int r = idx >> 4, seg = idx & 15;
            *(int4*)&Kt[r][seg * 8] =
                *(const int4*)(kf + ((size_t)kvh * SEQ + kt0 + r) * HD + seg * 8);
        }
#pragma unroll
        for (int it = 0; it < 8; ++it) {
            int idx = it * 128 + tid;
            int r = idx >> 3, seg = idx & 7;
            *(int4*)&Vt[r][seg * 8] =
                *(const int4*)(vT + ((size_t)kvh * HD + r) * SEQ + kt0 + seg * 8);
        }
        __syncthreads();

        f32x4 s[4];
#pragma unroll
        for (int nf = 0; nf < 4; ++nf) {
            f32x4 a = {0.f, 0.f, 0.f, 0.f};
#pragma unroll
            for (int c = 0; c < 4; ++c) {
                f16x8 bk = *(const f16x8*)&Kt[nf * 16 + lr][c * 32 + lg * 8];
                a = __builtin_amdgcn_mfma_f32_16x16x32_f16(aq[c], bk, a, 0, 0, 0);
            }
            s[nf] = a;
        }
        const float scale = 0.08838834764831845f;
        float tmax[4] = {-3e38f, -3e38f, -3e38f, -3e38f};
#pragma unroll
        for (int nf = 0; nf < 4; ++nf) {
            int ktg = kt0 + nf * 16 + lr;
#pragma unroll
            for (int ii = 0; ii < 4; ++ii) {
                int qg = qrow + lg * 4 + ii;
                float vv = s[nf][ii] * scale;
                vv = (ktg <= qg) ? vv : -1e30f;
                s[nf][ii] = vv;
                tmax[ii] = fmaxf(tmax[ii], vv);
            }
        }
#pragma unroll
        for (int m = 1; m < 16; m <<= 1)
#pragma unroll
            for (int ii = 0; ii < 4; ++ii)
                tmax[ii] = fmaxf(tmax[ii], __shfl_xor(tmax[ii], m));
        float corr[4];
#pragma unroll
        for (int ii = 0; ii < 4; ++ii) {
            float mnew = fmaxf(mrun[ii], tmax[ii]);
            corr[ii] = __expf(mrun[ii] - mnew);
            mrun[ii] = mnew;
        }
        float tsum[4] = {0.f, 0.f, 0.f, 0.f};
#pragma unroll
        for (int nf = 0; nf < 4; ++nf)
#pragma unroll
            for (int ii = 0; ii < 4; ++ii) {
                float pp = __expf(s[nf][ii] - mrun[ii]);
                s[nf][ii] = pp;
                tsum[ii] += pp;
            }
#pragma unroll
        for (int m = 1; m < 16; m <<= 1)
#pragma unroll
            for (int ii = 0; ii < 4; ++ii) tsum[ii] += __shfl_xor(tsum[ii], m);
#pragma unroll
        for (int ii = 0; ii < 4; ++ii) lrun[ii] = lrun[ii] * corr[ii] + tsum[ii];
#pragma unroll
        for (int df = 0; df < 8; ++df)
#pragma unroll
            for (int ii = 0; ii < 4; ++ii) accv[df][ii] *= corr[ii];
#pragma unroll
        for (int nf = 0; nf < 4; ++nf)
#pragma unroll
            for (int ii = 0; ii < 4; ++ii)
                Pl[wv][lg * 4 + ii][nf * 16 + lr] = (f16_t)s[nf][ii];
        __syncthreads();
#pragma unroll
        for (int c = 0; c < 2; ++c) {
            f16x8 ap = *(const f16x8*)&Pl[wv][lr][c * 32 + lg * 8];
#pragma unroll
            for (int df = 0; df < 8; ++df) {
                f16x8 bv = *(const f16x8*)&Vt[df * 16 + lr][c * 32 + lg * 8];
                accv[df] = __builtin_amdgcn_mfma_f32_16x16x32_f16(ap, bv, accv[df], 0, 0, 0);
            }
        }
    }
#pragma unroll
    for (int df = 0; df < 8; ++df)
#pragma unroll
        for (int ii = 0; ii < 4; ++ii) {
            int qg = qrow + lg * 4 + ii;
            out[(size_t)qg * 2048 + h * HD + df * 16 + lr] =
                (bf16_t)(accv[df][ii] / lrun[ii]);
        }
}

// ---------------------------------------------------------------------------
extern "C" void kernel_launch(void* const* d_in, const int* in_sizes, int n_in,
                              void* d_out, int out_size, void* d_ws, size_t ws_size,
                              hipStream_t stream)
{
    const float* hin  = (const float*)d_in[0];
    const float* cosb = (const float*)d_in[1];
    const float* sinb = (const float*)d_in[2];
    const float* Wq = (const float*)d_in[4];
    const float* Wk = (const float*)d_in[5];
    const float* Wv = (const float*)d_in[6];
    const float* Wo = (const float*)d_in[7];
    const float* Wg = (const float*)d_in[8];
    const float* Wu = (const float*)d_in[9];
    const float* Wd = (const float*)d_in[10];
    const float* Ln1 = (const float*)d_in[11];
    const float* Ln2 = (const float*)d_in[12];
    const float* Qn = (const float*)d_in[13];
    const float* Kn = (const float*)d_in[14];

    char* p = (char*)d_ws;
    auto alloc = [&](size_t bytes) { char* r = p; p += bytes; return r; };
    float* h     = (float*)alloc((size_t)SEQ * 1024 * 4);
    float* parts = (float*)alloc((size_t)4 * SEQ * 1024 * 4);
    f16_t* qkvh  = (f16_t*)alloc((size_t)SEQ * 4096 * 2);
    bf16_t* x     = (bf16_t*)alloc((size_t)SEQ * 1024 * 2);
    bf16_t* y     = (bf16_t*)alloc((size_t)SEQ * 1024 * 2);
    bf16_t* attnb = (bf16_t*)alloc((size_t)SEQ * 2048 * 2);
    bf16_t* mbuf  = (bf16_t*)alloc((size_t)SEQ * 3072 * 2);
    f16_t* qf = (f16_t*)alloc((size_t)NHQ * SEQ * HD * 2);
    f16_t* kf = (f16_t*)alloc((size_t)NHKV * SEQ * HD * 2);
    f16_t* vT = (f16_t*)alloc((size_t)NHKV * HD * SEQ * 2);

    hipMemcpyAsync(h, hin, (size_t)SEQ * 1024 * 4, hipMemcpyDeviceToDevice, stream);

    for (int l = 0; l < 28; ++l) {
        const float* wq = Wq + (size_t)l * 1024 * 2048;
        const float* wk = Wk + (size_t)l * 1024 * 1024;
        const float* wv = Wv + (size_t)l * 1024 * 1024;
        const float* wo = Wo + (size_t)l * 2048 * 1024;
        const float* wg = Wg + (size_t)l * 1024 * 3072;
        const float* wu = Wu + (size_t)l * 1024 * 3072;
        const float* wd = Wd + (size_t)l * 3072 * 1024;

        k_resid_rms<<<512, 256, 0, stream>>>(h, parts, l == 0 ? 0 : 4,
                                             Ln1 + (size_t)l * 1024, x);
        // qkv (f16 out): N=4096, grid 8m x 64bn
        gemm_k<1, 2><<<512, 256, 0, stream>>>(x, 1024, wq, 2048, wk, 1024, wv,
                                              qkvh, 4096, (size_t)0, 1024);
        k_qknr<<<3072, 256, 0, stream>>>(qkvh, Qn + (size_t)l * 128,
                                         Kn + (size_t)l * 128, cosb, sinb, qf, kf);
        k_vtrans<<<32, 256, 0, stream>>>(qkvh, vT);
        k_attn<<<256, 128, 0, stream>>>(qf, kf, vT, attnb);
        // attn @ Wo: split-K4, grid 8m x (16bn*4)
        gemm_k<4, 0><<<512, 256, 0, stream>>>(attnb, 2048, wo, 1024, nullptr, 0,
                                              nullptr, parts, 1024,
                                              (size_t)SEQ * 1024, 2048);
        k_resid_rms<<<512, 256, 0, stream>>>(h, parts, 4,
                                             Ln2 + (size_t)l * 1024, y);
        // fused gate/up + silu: 96 paired col-tiles, grid 8m x 96
        gemm_k<1, 1><<<768, 256, 0, stream>>>(y, 1024, wg, 0, wu, 3072, nullptr,
                                              mbuf, 3072, (size_t)0, 1024);
        // down proj: split-K4
        gemm_k<4, 0><<<512, 256, 0, stream>>>(mbuf, 3072, wd, 1024, nullptr, 0,
                                              nullptr, parts, 1024,
                                              (size_t)SEQ * 1024, 3072);
    }
    k_finalize<<<512, 256, 0, stream>>>(h, parts, (float*)d_out);
}

// Round 3
// 3313.338 us; speedup vs baseline: 1.3279x; 1.2189x over previous
//
#include <hip/hip_runtime.h>
#include <stdint.h>

// Qwen3 decoder, 28L, Q=512, D=1024, HQ=16, HKV=8, HD=128, DFF=3072.
// R3: weights pre-converted to bf16 into pre-swizzled/transposed 64x64 tile
// images once per call; GEMMs use global_load_lds (no ds_writes/cvt in loop),
// BM64/BN256/BK64, 4 waves x (64x64/wave), double-buffered LDS.

typedef __bf16 bf16_t;
typedef _Float16 f16_t;
typedef __bf16 bf16x8 __attribute__((ext_vector_type(8)));
typedef __bf16 bf16x4 __attribute__((ext_vector_type(4)));
typedef _Float16 f16x8 __attribute__((ext_vector_type(8)));
typedef _Float16 f16x4 __attribute__((ext_vector_type(4)));
typedef float f32x4 __attribute__((ext_vector_type(4)));

#define SEQ 512
#define NHQ 16
#define NHKV 8
#define HD 128

// layer image section offsets (bytes) inside one 30MB weight image
#define IMG_QKV 0ull
#define IMG_WO  8388608ull
#define IMG_GU  12582912ull
#define IMG_WD  25165824ull
#define IMG_LAYER_BYTES 31457280ull

typedef const __attribute__((address_space(1))) uint32_t as1_u32;
typedef __attribute__((address_space(3))) uint32_t as3_u32;

__device__ __forceinline__ void gload16(const void* g, void* l) {
    __builtin_amdgcn_global_load_lds((as1_u32*)g, (as3_u32*)l, 16, 0, 0);
}

// byte offset into a tiled-swizzled A image (64x64 bf16 tiles, 8KB each).
// ldak = K/64 tiles per row-block. swizzle: byte-col XOR ((row&7)<<4).
__device__ __forceinline__ size_t aoff(int row, int col, int ldak) {
    return (((size_t)((row >> 6) * ldak + (col >> 6))) << 13) +
           ((size_t)(row & 63) << 7) +
           (size_t)((((col & 63) << 1)) ^ ((row & 7) << 4));
}

// ---------------------------------------------------------------------------
// weight pre-convert: fp32 -> bf16, [k][n] -> [n][k] 64x64 units, swizzled.
__global__ __launch_bounds__(256) void k_conv(
    const float* __restrict__ Wq, const float* __restrict__ Wk,
    const float* __restrict__ Wv, const float* __restrict__ Wo,
    const float* __restrict__ Wg, const float* __restrict__ Wu,
    const float* __restrict__ Wd, int l0, char* __restrict__ img)
{
    int lay = l0 + blockIdx.y;
    const float* wq = Wq + (size_t)lay * 1024 * 2048;
    const float* wk = Wk + (size_t)lay * 1024 * 1024;
    const float* wv = Wv + (size_t)lay * 1024 * 1024;
    const float* wo = Wo + (size_t)lay * 2048 * 1024;
    const float* wg = Wg + (size_t)lay * 1024 * 3072;
    const float* wu = Wu + (size_t)lay * 1024 * 3072;
    const float* wd = Wd + (size_t)lay * 3072 * 1024;
    char* ib = img + (size_t)blockIdx.y * IMG_LAYER_BYTES;

    int b = blockIdx.x;
    const float* src = nullptr;
    int ldbw = 0, bn, kt, q;
    int guMode = 0;
    size_t dstoff;
    if (b < 1024) {                       // qkv: 16 bn x 16 kt x 4 q
        q = b & 3; kt = (b >> 2) & 15; bn = b >> 6;
        int C0 = bn * 256 + q * 64;
        if (C0 < 2048)      { src = wq + C0;          ldbw = 2048; }
        else if (C0 < 3072) { src = wk + (C0 - 2048); ldbw = 1024; }
        else                { src = wv + (C0 - 3072); ldbw = 1024; }
        src += (size_t)(kt * 64) * ldbw;
        dstoff = IMG_QKV + (size_t)b * 8192;
    } else if (b < 1536) {                // wo: 4 bn x 32 kt x 4 q
        int b2 = b - 1024; q = b2 & 3; kt = (b2 >> 2) & 31; bn = b2 >> 7;
        src = wo + (size_t)(kt * 64) * 1024 + bn * 256 + q * 64; ldbw = 1024;
        dstoff = IMG_WO + (size_t)b2 * 8192;
    } else if (b < 3072) {                // gu: 24 bn x 16 kt x 4 q (g/u interleaved by 16)
        int b3 = b - 1536; q = b3 & 3; kt = (b3 >> 2) & 15; bn = b3 >> 6;
        guMode = 1; ldbw = 3072;
        dstoff = IMG_GU + (size_t)b3 * 8192;
    } else {                              // wd: 4 bn x 48 kt x 4 q
        int b4 = b - 3072; q = b4 & 3; int x = b4 >> 2; kt = x % 48; bn = x / 48;
        src = wd + (size_t)(kt * 64) * 1024 + bn * 256 + q * 64; ldbw = 1024;
        dstoff = IMG_WD + (size_t)b4 * 8192;
    }

    __shared__ float T[64][68];
    int tid = threadIdx.x;
    if (!guMode) {
#pragma unroll
        for (int it = 0; it < 4; ++it) {
            int idx = it * 256 + tid;
            int kk = idx >> 4, seg = idx & 15;
            *(float4*)&T[kk][seg * 4] = *(const float4*)(src + (size_t)kk * ldbw + seg * 4);
        }
    } else {
        const float* wg_ = wg + (size_t)(kt * 64) * 3072;
        const float* wu_ = wu + (size_t)(kt * 64) * 3072;
#pragma unroll
        for (int it = 0; it < 4; ++it) {
            int idx = it * 256 + tid;
            int kk = idx >> 4, seg = idx & 15;
            int nl = seg * 4;
            int colc = bn * 128 + q * 32 + ((nl >> 5) & 1) * 16 + (nl & 15);
            const float* s2 = (((nl >> 4) & 1) ? wu_ : wg_) + (size_t)kk * 3072 + colc;
            *(float4*)&T[kk][nl] = *(const float4*)s2;
        }
    }
    __syncthreads();
    char* dst = ib + dstoff;
#pragma unroll
    for (int it = 0; it < 2; ++it) {
        int kg = tid & 7;
        int n = it * 32 + (tid >> 3);
        bf16x8 o;
#pragma unroll
        for (int j = 0; j < 8; ++j) o[j] = (bf16_t)T[kg * 8 + j][n];
        *(bf16x8*)(dst + n * 128 + ((kg * 16) ^ ((n & 7) << 4))) = o;
    }
}

// ---------------------------------------------------------------------------
// residual(+8 splitK partials) + RMSNorm -> bf16 tiled-swizzled image
__global__ __launch_bounds__(256) void k_rms(
    float* __restrict__ h, const float* __restrict__ parts, int nparts,
    const float* __restrict__ w, char* __restrict__ ximg)
{
    int t = blockIdx.x, tid = threadIdx.x;
    size_t base = (size_t)t * 1024 + tid * 4;
    float4 v = *(const float4*)(h + base);
    for (int p = 0; p < nparts; ++p) {
        float4 a = *(const float4*)(parts + (size_t)p * 524288 + base);
        v.x += a.x; v.y += a.y; v.z += a.z; v.w += a.w;
    }
    if (nparts) *(float4*)(h + base) = v;
    float ss = v.x * v.x + v.y * v.y + v.z * v.z + v.w * v.w;
#pragma unroll
    for (int m = 1; m < 64; m <<= 1) ss += __shfl_xor(ss, m);
    __shared__ float red[4];
    if ((tid & 63) == 0) red[tid >> 6] = ss;
    __syncthreads();
    float tot = (red[0] + red[1]) + (red[2] + red[3]);
    float sc = rsqrtf(tot * (1.0f / 1024.0f) + 1e-6f);
    float4 wv4 = *(const float4*)(w + tid * 4);
    bf16x4 o;
    o[0] = (bf16_t)(v.x * sc * wv4.x);
    o[1] = (bf16_t)(v.y * sc * wv4.y);
    o[2] = (bf16_t)(v.z * sc * wv4.z);
    o[3] = (bf16_t)(v.w * sc * wv4.w);
    *(bf16x4*)(ximg + aoff(t, tid * 4, 16)) = o;
}

// ---------------------------------------------------------------------------
__global__ __launch_bounds__(256) void k_finalize(
    const float* __restrict__ h, const float* __restrict__ parts,
    float* __restrict__ out)
{
    size_t base = ((size_t)blockIdx.x * 256 + threadIdx.x) * 4;
    float4 v = *(const float4*)(h + base);
#pragma unroll
    for (int p = 0; p < 8; ++p) {
        float4 a = *(const float4*)(parts + (size_t)p * 524288 + base);
        v.x += a.x; v.y += a.y; v.z += a.z; v.w += a.w;
    }
    *(float4*)(out + base) = v;
}

// ---------------------------------------------------------------------------
// GEMM core: C[512,N] = Aimg(bf16 tiles) @ Bimg(bf16 tiles).
// BM=64, BN=256, BK=64, 4 waves each 64x64 (4x4 frags). global_load_lds only.
// MODE 0: fp32 split-K partials. MODE 1: gu paired swiglu -> mbuf image.
// MODE 2: f16 plain out (qkv).
template <int SPLITK, int MODE>
__device__ __forceinline__ void gemm_core(
    const char* __restrict__ Aimg, int ldak,
    const char* __restrict__ Bimg, void* __restrict__ outp)
{
    const int steps = ldak / SPLITK;
    int f = blockIdx.x;
    int xc = f & 7, tt = f >> 3;
    int bm = tt & 7;
    int g = xc + 8 * (tt >> 3);
    int bn, s;
    if (MODE == 0) { bn = g & 3; s = g >> 2; }
    else           { bn = g;     s = 0;      }
    int k0d = s * steps;

    __shared__ __align__(128) char smem[81920];  // 2 x (A 8KB + B 32KB)

    int tid = threadIdx.x;
    int wv = tid >> 6, l = tid & 63, lg = l >> 4, lr = l & 15;

    const char* Ab = Aimg + ((size_t)(bm * ldak + k0d)) * 8192;
    const char* Bb = Bimg + ((size_t)(bn * ldak + k0d)) * 32768;

    f32x4 acc[4][4];
#pragma unroll
    for (int i = 0; i < 4; ++i)
#pragma unroll
        for (int j = 0; j < 4; ++j) { f32x4 z = {0.f, 0.f, 0.f, 0.f}; acc[i][j] = z; }

    auto stage = [&](int buf, int kt) {
        const char* ab = Ab + (size_t)kt * 8192;
        const char* bb = Bb + (size_t)kt * 32768;
        char* al = smem + buf * 40960;
        char* bl = al + 8192;
#pragma unroll
        for (int u = 0; u < 2; ++u) {
            int off = (u * 4 + wv) * 1024;
            gload16(ab + off + l * 16, al + off);
        }
#pragma unroll
        for (int u = 0; u < 8; ++u) {
            int off = (u * 4 + wv) * 1024;
            gload16(bb + off + l * 16, bl + off);
        }
    };
    auto compute = [&](int buf) {
        const char* as = smem + buf * 40960;
        const char* bs = as + 8192;
#pragma unroll
        for (int c = 0; c < 2; ++c) {
            int co = (c * 64 + lg * 16) ^ ((lr & 7) << 4);
            bf16x8 af[4], bf[4];
#pragma unroll
            for (int i = 0; i < 4; ++i)
                af[i] = *(const bf16x8*)(as + (i * 16 + lr) * 128 + co);
#pragma unroll
            for (int j = 0; j < 4; ++j)
                bf[j] = *(const bf16x8*)(bs + (wv * 64 + j * 16 + lr) * 128 + co);
#pragma unroll
            for (int i = 0; i < 4; ++i)
#pragma unroll
                for (int j = 0; j < 4; ++j)
                    acc[i][j] = __builtin_amdgcn_mfma_f32_16x16x32_bf16(
                        af[i], bf[j], acc[i][j], 0, 0, 0);
        }
    };

    stage(0, 0);
    __syncthreads();
    int buf = 0;
    for (int kt = 0; kt < steps; ++kt) {
        if (kt + 1 < steps) stage(buf ^ 1, kt + 1);
        compute(buf);
        __syncthreads();
        buf ^= 1;
    }

    if (MODE == 0) {
        float* P = (float*)outp + (size_t)s * 524288;
#pragma unroll
        for (int i = 0; i < 4; ++i)
#pragma unroll
            for (int j = 0; j < 4; ++j)
#pragma unroll
                for (int ii = 0; ii < 4; ++ii) {
                    int row = bm * 64 + i * 16 + lg * 4 + ii;
                    int col = bn * 256 + wv * 64 + j * 16 + lr;
                    P[(size_t)row * 1024 + col] = acc[i][j][ii];
                }
    } else if (MODE == 2) {
        f16_t* Q = (f16_t*)outp;
#pragma unroll
        for (int i = 0; i < 4; ++i)
#pragma unroll
            for (int j = 0; j < 4; ++j)
#pragma unroll
                for (int ii = 0; ii < 4; ++ii) {
                    int row = bm * 64 + i * 16 + lg * 4 + ii;
                    int col = bn * 256 + wv * 64 + j * 16 + lr;
                    Q[(size_t)row * 4096 + col] = (f16_t)acc[i][j][ii];
                }
    } else {
        char* M = (char*)outp;
#pragma unroll
        for (int i = 0; i < 4; ++i)
#pragma unroll
            for (int jp = 0; jp < 2; ++jp)
#pragma unroll
                for (int ii = 0; ii < 4; ++ii) {
                    int row = bm * 64 + i * 16 + lg * 4 + ii;
                    int col = bn * 128 + wv * 32 + jp * 16 + lr;
                    float gv = acc[i][2 * jp][ii];
                    float uv = acc[i][2 * jp + 1][ii];
                    float val = gv / (1.f + __expf(-gv)) * uv;
                    *(bf16_t*)(M + aoff(row, col, 48)) = (bf16_t)val;
                }
    }
}

__global__ __launch_bounds__(256) void g_qkv(const char* A, const char* B, f16_t* out)
{ gemm_core<1, 2>(A, 16, B, out); }
__global__ __launch_bounds__(256) void g_wo(const char* A, const char* B, float* parts)
{ gemm_core<8, 0>(A, 32, B, parts); }
__global__ __launch_bounds__(256) void g_gu(const char* A, const char* B, char* mimg)
{ gemm_core<1, 1>(A, 16, B, mimg); }
__global__ __launch_bounds__(256) void g_wd(const char* A, const char* B, float* parts)
{ gemm_core<8, 0>(A, 48, B, parts); }

// ---------------------------------------------------------------------------
// q/k head RMSNorm + RoPE (one wave per (token, slot)); qkvh is f16 plain.
__global__ __launch_bounds__(256) void k_qknr(
    const f16_t* __restrict__ qkvh,
    const float* __restrict__ qw, const float* __restrict__ kw,
    const float* __restrict__ cosb, const float* __restrict__ sinb,
    f16_t* __restrict__ qf, f16_t* __restrict__ kf)
{
    int tid = threadIdx.x;
    int idx = blockIdx.x * 4 + (tid >> 6);
    int slot = idx % 24;
    int t = idx / 24;
    int d = tid & 63;
    bool isq = slot < 16;
    int col = isq ? slot * HD + d : 2048 + (slot - 16) * HD + d;
    const f16_t* row = qkvh + (size_t)t * 4096;
    float x1 = (float)row[col];
    float x2 = (float)row[col + 64];
    float ss = x1 * x1 + x2 * x2;
#pragma unroll
    for (int m = 1; m < 64; m <<= 1) ss += __shfl_xor(ss, m);
    float sc = rsqrtf(ss * (1.0f / 128.0f) + 1e-6f);
    float w1 = isq ? qw[d] : kw[d];
    float w2 = isq ? qw[d + 64] : kw[d + 64];
    float xn1 = x1 * sc * w1, xn2 = x2 * sc * w2;
    float o1 = xn1 * cosb[t * HD + d] - xn2 * sinb[t * HD + d];
    float o2 = xn2 * cosb[t * HD + d + 64] + xn1 * sinb[t * HD + d + 64];
    if (isq) {
        f16_t* o = qf + ((size_t)slot * SEQ + t) * HD;
        o[d] = (f16_t)o1; o[d + 64] = (f16_t)o2;
    } else {
        f16_t* o = kf + ((size_t)(slot - 16) * SEQ + t) * HD;
        o[d] = (f16_t)o1; o[d + 64] = (f16_t)o2;
    }
}

// ---------------------------------------------------------------------------
// V transpose: qkvh v-part -> vT f16 [kvh][d][t]
__global__ __launch_bounds__(256) void k_vtrans(
    const f16_t* __restrict__ qkvh, f16_t* __restrict__ vT)
{
    int kvh = blockIdx.x >> 2, tb = blockIdx.x & 3;
    __shared__ f16_t tileS[128][136];
    int tid = threadIdx.x;
#pragma unroll
    for (int it = 0; it < 8; ++it) {
        int r = it * 16 + (tid >> 4);
        int cs = tid & 15;
        f16x8 v = *(const f16x8*)(qkvh + (size_t)(tb * 128 + r) * 4096 + 3072 + kvh * HD + cs * 8);
        *(f16x8*)&tileS[r][cs * 8] = v;
    }
    __syncthreads();
#pragma unroll
    for (int it = 0; it < 8; ++it) {
        int dr = it * 16 + (tid >> 4);
        int seg = tid & 15;
        f16x8 o;
#pragma unroll
        for (int j = 0; j < 8; ++j) o[j] = tileS[seg * 8 + j][dr];
        *(f16x8*)(vT + ((size_t)kvh * HD + dr) * SEQ + tb * 128 + seg * 8) = o;
    }
}

// ---------------------------------------------------------------------------
// causal flash attention -> attn-out image (tiled-swizzled bf16)
__global__ __launch_bounds__(128) void k_attn(
    const f16_t* __restrict__ qf, const f16_t* __restrict__ kf,
    const f16_t* __restrict__ vT, char* __restrict__ attimg)
{
    int h = blockIdx.x >> 4, qb = blockIdx.x & 15;
    int kvh = h >> 1;
    __shared__ f16_t Kt[64][136];
    __shared__ f16_t Vt[128][72];
    __shared__ f16_t Pl[2][16][72];
    int tid = threadIdx.x;
    int wv = tid >> 6, l = tid & 63, lg = l >> 4, lr = l & 15;
    int q0 = qb * 32;
    int qrow = q0 + wv * 16;

    f16x8 aq[4];
    const f16_t* qp = qf + ((size_t)h * SEQ + qrow + lr) * HD;
#pragma unroll
    for (int c = 0; c < 4; ++c) aq[c] = *(const f16x8*)(qp + c * 32 + lg * 8);

    f32x4 accv[8];
#pragma unroll
    for (int df = 0; df < 8; ++df) { f32x4 z = {0.f, 0.f, 0.f, 0.f}; accv[df] = z; }
    float mrun[4], lrun[4];
#pragma unroll
    for (int ii = 0; ii < 4; ++ii) { mrun[ii] = -3e38f; lrun[ii] = 0.f; }

    int ktiles = (q0 + 32 + 63) >> 6;
    for (int kt = 0; kt < ktiles; ++kt) {
        int kt0 = kt * 64;
        __syncthreads();
#pragma unroll
        for (int it = 0; it < 8; ++it) {
            int idx = it * 128 + tid;
            int r = idx >> 4, seg = idx & 15;
            *(int4*)&Kt[r][seg * 8] =
                *(const int4*)(kf + ((size_t)kvh * SEQ + kt0 + r) * HD + seg * 8);
        }
#pragma unroll
        for (int it = 0; it < 8; ++it) {
            int idx = it * 128 + tid;
            int r = idx >> 3, seg = idx & 7;
            *(int4*)&Vt[r][seg * 8] =
                *(const int4*)(vT + ((size_t)kvh * HD + r) * SEQ + kt0 + seg * 8);
        }
        __syncthreads();

        f32x4 s[4];
#pragma unroll
        for (int nf = 0; nf < 4; ++nf) {
            f32x4 a = {0.f, 0.f, 0.f, 0.f};
#pragma unroll
            for (int c = 0; c < 4; ++c) {
                f16x8 bk = *(const f16x8*)&Kt[nf * 16 + lr][c * 32 + lg * 8];
                a = __builtin_amdgcn_mfma_f32_16x16x32_f16(aq[c], bk, a, 0, 0, 0);
            }
            s[nf] = a;
        }
        const float scale = 0.08838834764831845f;
        float tmax[4] = {-3e38f, -3e38f, -3e38f, -3e38f};
#pragma unroll
        for (int nf = 0; nf < 4; ++nf) {
            int ktg = kt0 + nf * 16 + lr;
#pragma unroll
            for (int ii = 0; ii < 4; ++ii) {
                int qg = qrow + lg * 4 + ii;
                float vv = s[nf][ii] * scale;
                vv = (ktg <= qg) ? vv : -1e30f;
                s[nf][ii] = vv;
                tmax[ii] = fmaxf(tmax[ii], vv);
            }
        }
#pragma unroll
        for (int m = 1; m < 16; m <<= 1)
#pragma unroll
            for (int ii = 0; ii < 4; ++ii)
                tmax[ii] = fmaxf(tmax[ii], __shfl_xor(tmax[ii], m));
        float corr[4];
#pragma unroll
        for (int ii = 0; ii < 4; ++ii) {
            float mnew = fmaxf(mrun[ii], tmax[ii]);
            corr[ii] = __expf(mrun[ii] - mnew);
            mrun[ii] = mnew;
        }
        float tsum[4] = {0.f, 0.f, 0.f, 0.f};
#pragma unroll
        for (int nf = 0; nf < 4; ++nf)
#pragma unroll
            for (int ii = 0; ii < 4; ++ii) {
                float pp = __expf(s[nf][ii] - mrun[ii]);
                s[nf][ii] = pp;
                tsum[ii] += pp;
            }
#pragma unroll
        for (int m = 1; m < 16; m <<= 1)
#pragma unroll
            for (int ii = 0; ii < 4; ++ii) tsum[ii] += __shfl_xor(tsum[ii], m);
#pragma unroll
        for (int ii = 0; ii < 4; ++ii) lrun[ii] = lrun[ii] * corr[ii] + tsum[ii];
#pragma unroll
        for (int df = 0; df < 8; ++df)
#pragma unroll
            for (int ii = 0; ii < 4; ++ii) accv[df][ii] *= corr[ii];
#pragma unroll
        for (int nf = 0; nf < 4; ++nf)
#pragma unroll
            for (int ii = 0; ii < 4; ++ii)
                Pl[wv][lg * 4 + ii][nf * 16 + lr] = (f16_t)s[nf][ii];
        __syncthreads();
#pragma unroll
        for (int c = 0; c < 2; ++c) {
            f16x8 ap = *(const f16x8*)&Pl[wv][lr][c * 32 + lg * 8];
#pragma unroll
            for (int df = 0; df < 8; ++df) {
                f16x8 bv = *(const f16x8*)&Vt[df * 16 + lr][c * 32 + lg * 8];
                accv[df] = __builtin_amdgcn_mfma_f32_16x16x32_f16(ap, bv, accv[df], 0, 0, 0);
            }
        }
    }
#pragma unroll
    for (int df = 0; df < 8; ++df)
#pragma unroll
        for (int ii = 0; ii < 4; ++ii) {
            int qg = qrow + lg * 4 + ii;
            int col = h * HD + df * 16 + lr;
            *(bf16_t*)(attimg + aoff(qg, col, 32)) =
                (bf16_t)(accv[df][ii] / lrun[ii]);
        }
}

// ---------------------------------------------------------------------------
extern "C" void kernel_launch(void* const* d_in, const int* in_sizes, int n_in,
                              void* d_out, int out_size, void* d_ws, size_t ws_size,
                              hipStream_t stream)
{
    const float* hin  = (const float*)d_in[0];
    const float* cosb = (const float*)d_in[1];
    const float* sinb = (const float*)d_in[2];
    const float* Wq = (const float*)d_in[4];
    const float* Wk = (const float*)d_in[5];
    const float* Wv = (const float*)d_in[6];
    const float* Wo = (const float*)d_in[7];
    const float* Wg = (const float*)d_in[8];
    const float* Wu = (const float*)d_in[9];
    const float* Wd = (const float*)d_in[10];
    const float* Ln1 = (const float*)d_in[11];
    const float* Ln2 = (const float*)d_in[12];
    const float* Qn = (const float*)d_in[13];
    const float* Kn = (const float*)d_in[14];

    char* p = (char*)d_ws;
    auto alloc = [&](size_t bytes) { char* r = p; p += bytes; return r; };
    float* h     = (float*)alloc(2097152);
    float* parts = (float*)alloc(16777216);          // 8 x 2MB splitK partials
    char*  ximg  = alloc(1048576);
    char*  yimg  = alloc(1048576);
    char*  attimg= alloc(2097152);
    char*  mimg  = alloc(3145728);
    f16_t* qkvh  = (f16_t*)alloc(4194304);
    f16_t* qf    = (f16_t*)alloc(2097152);
    f16_t* kf    = (f16_t*)alloc(1048576);
    f16_t* vT    = (f16_t*)alloc(1048576);
    char*  wimg  = alloc(0);
    size_t fixed = (size_t)(wimg - (char*)d_ws);
    bool upfront = ws_size >= fixed + 28ull * IMG_LAYER_BYTES;

    hipMemcpyAsync(h, hin, 2097152, hipMemcpyDeviceToDevice, stream);

    if (upfront)
        k_conv<<<dim3(3840, 28), 256, 0, stream>>>(Wq, Wk, Wv, Wo, Wg, Wu, Wd, 0, wimg);

    for (int l = 0; l < 28; ++l) {
        const char* img = upfront ? wimg + (size_t)l * IMG_LAYER_BYTES : wimg;
        if (!upfront)
            k_conv<<<dim3(3840, 1), 256, 0, stream>>>(Wq, Wk, Wv, Wo, Wg, Wu, Wd, l, wimg);

        k_rms<<<512, 256, 0, stream>>>(h, parts, l == 0 ? 0 : 8,
                                       Ln1 + (size_t)l * 1024, ximg);
        g_qkv<<<128, 256, 0, stream>>>(ximg, img + IMG_QKV, qkvh);
        k_qknr<<<3072, 256, 0, stream>>>(qkvh, Qn + (size_t)l * 128,
                                         Kn + (size_t)l * 128, cosb, sinb, qf, kf);
        k_vtrans<<<32, 256, 0, stream>>>(qkvh, vT);
        k_attn<<<256, 128, 0, stream>>>(qf, kf, vT, attimg);
        g_wo<<<256, 256, 0, stream>>>(attimg, img + IMG_WO, parts);
        k_rms<<<512, 256, 0, stream>>>(h, parts, 8, Ln2 + (size_t)l * 1024, yimg);
        g_gu<<<192, 256, 0, stream>>>(yimg, img + IMG_GU, mimg);
        g_wd<<<256, 256, 0, stream>>>(mimg, img + IMG_WD, parts);
    }
    k_finalize<<<512, 256, 0, stream>>>(h, parts, (float*)d_out);
}

// Round 4
// 2567.648 us; speedup vs baseline: 1.7135x; 1.2904x over previous
//
#include <hip/hip_runtime.h>
#include <stdint.h>

// Qwen3 decoder, 28L, Q=512, D=1024, HQ=16, HKV=8, HD=128, DFF=3072.
// R4: per-layer weight conv (L3-resident images) fused into previous wd;
// GEMM 64x128x64, 4 waves, 48KB dbuf LDS (3 blocks/CU); split-K4 bf16
// partials; qknorm+rope+vtrans merged; copy kernel instead of memcpy.

typedef __bf16 bf16_t;
typedef _Float16 f16_t;
typedef __bf16 bf16x8 __attribute__((ext_vector_type(8)));
typedef __bf16 bf16x4 __attribute__((ext_vector_type(4)));
typedef _Float16 f16x8 __attribute__((ext_vector_type(8)));
typedef _Float16 f16x4 __attribute__((ext_vector_type(4)));
typedef float f32x4 __attribute__((ext_vector_type(4)));

#define SEQ 512
#define NHQ 16
#define NHKV 8
#define HD 128

#define IMG_QKV 0ull
#define IMG_WO  8388608ull
#define IMG_GU  12582912ull
#define IMG_WD  25165824ull
#define IMG_LAYER_BYTES 31457280ull

typedef const __attribute__((address_space(1))) uint32_t as1_u32;
typedef __attribute__((address_space(3))) uint32_t as3_u32;

__device__ __forceinline__ void gload16(const void* g, void* l) {
    __builtin_amdgcn_global_load_lds((as1_u32*)g, (as3_u32*)l, 16, 0, 0);
}

// byte offset into tiled-swizzled image (64x64 bf16 tiles, 8KB, [rowblk][kt])
__device__ __forceinline__ size_t aoff(int row, int col, int ldak) {
    return (((size_t)((row >> 6) * ldak + (col >> 6))) << 13) +
           ((size_t)(row & 63) << 7) +
           (size_t)((((col & 63) << 1)) ^ ((row & 7) << 4));
}

// ---------------------------------------------------------------------------
__global__ __launch_bounds__(256) void k_copy(const float* __restrict__ src,
                                              float* __restrict__ dst)
{
    size_t i = ((size_t)blockIdx.x * 256 + threadIdx.x) * 4;
    *(float4*)(dst + i) = *(const float4*)(src + i);
}

// ---------------------------------------------------------------------------
// weight tile convert: one 64x64 tile per block. Uniform [n][kt] tile order.
__device__ __forceinline__ void conv_tile(
    int b, int lay,
    const float* __restrict__ Wq, const float* __restrict__ Wk,
    const float* __restrict__ Wv, const float* __restrict__ Wo,
    const float* __restrict__ Wg, const float* __restrict__ Wu,
    const float* __restrict__ Wd, char* __restrict__ ib, void* smemv)
{
    const float* wq = Wq + (size_t)lay * 1024 * 2048;
    const float* wk = Wk + (size_t)lay * 1024 * 1024;
    const float* wv = Wv + (size_t)lay * 1024 * 1024;
    const float* wo = Wo + (size_t)lay * 2048 * 1024;
    const float* wg = Wg + (size_t)lay * 1024 * 3072;
    const float* wu = Wu + (size_t)lay * 1024 * 3072;
    const float* wd = Wd + (size_t)lay * 3072 * 1024;

    const float* src = nullptr;
    int ldbw = 0, n, kt, guMode = 0;
    size_t dstoff;
    if (b < 1024) {                      // qkv: 64 n x 16 kt
        n = b >> 4; kt = b & 15;
        int C0 = n * 64;
        if (C0 < 2048)      { src = wq + C0;          ldbw = 2048; }
        else if (C0 < 3072) { src = wk + (C0 - 2048); ldbw = 1024; }
        else                { src = wv + (C0 - 3072); ldbw = 1024; }
        src += (size_t)(kt * 64) * ldbw;
        dstoff = IMG_QKV + (size_t)b * 8192;
    } else if (b < 1536) {               // wo: 16 n x 32 kt
        int b2 = b - 1024; n = b2 >> 5; kt = b2 & 31;
        src = wo + (size_t)(kt * 64) * 1024 + n * 64; ldbw = 1024;
        dstoff = IMG_WO + (size_t)b2 * 8192;
    } else if (b < 3072) {               // gu: 96 n x 16 kt (g/u 16-interleave)
        int b3 = b - 1536; n = b3 >> 4; kt = b3 & 15;
        guMode = 1; ldbw = 3072;
        dstoff = IMG_GU + (size_t)b3 * 8192;
    } else {                             // wd: 16 n x 48 kt
        int b4 = b - 3072; n = b4 / 48; kt = b4 % 48;
        src = wd + (size_t)(kt * 64) * 1024 + n * 64; ldbw = 1024;
        dstoff = IMG_WD + (size_t)b4 * 8192;
    }

    float (*T)[68] = (float (*)[68])smemv;
    int tid = threadIdx.x;
    if (!guMode) {
#pragma unroll
        for (int it = 0; it < 4; ++it) {
            int idx = it * 256 + tid;
            int kk = idx >> 4, seg = idx & 15;
            *(float4*)&T[kk][seg * 4] = *(const float4*)(src + (size_t)kk * ldbw + seg * 4);
        }
    } else {
        const float* wg_ = wg + (size_t)(kt * 64) * 3072;
        const float* wu_ = wu + (size_t)(kt * 64) * 3072;
#pragma unroll
        for (int it = 0; it < 4; ++it) {
            int idx = it * 256 + tid;
            int kk = idx >> 4, seg = idx & 15;
            int nl = seg * 4;
            int colc = n * 32 + ((nl >> 5) & 1) * 16 + (nl & 15);
            const float* s2 = (((nl >> 4) & 1) ? wu_ : wg_) + (size_t)kk * 3072 + colc;
            *(float4*)&T[kk][nl] = *(const float4*)s2;
        }
    }
    __syncthreads();
    char* dst = ib + dstoff;
#pragma unroll
    for (int it = 0; it < 2; ++it) {
        int kg = tid & 7;
        int nrow = it * 32 + (tid >> 3);
        bf16x8 o;
#pragma unroll
        for (int j = 0; j < 8; ++j) o[j] = (bf16_t)T[kg * 8 + j][nrow];
        *(bf16x8*)(dst + nrow * 128 + ((kg * 16) ^ ((nrow & 7) << 4))) = o;
    }
}

__global__ __launch_bounds__(256) void k_conv(
    int lay,
    const float* __restrict__ Wq, const float* __restrict__ Wk,
    const float* __restrict__ Wv, const float* __restrict__ Wo,
    const float* __restrict__ Wg, const float* __restrict__ Wu,
    const float* __restrict__ Wd, char* __restrict__ img)
{
    __shared__ __align__(16) char smem[17408];
    conv_tile(blockIdx.x, lay, Wq, Wk, Wv, Wo, Wg, Wu, Wd, img, smem);
}

// ---------------------------------------------------------------------------
// residual(+4 bf16 splitK partials) + RMSNorm -> bf16 tiled-swizzled image
__global__ __launch_bounds__(256) void k_rms(
    float* __restrict__ h, const bf16_t* __restrict__ parts, int nparts,
    const float* __restrict__ w, char* __restrict__ ximg)
{
    int t = blockIdx.x, tid = threadIdx.x;
    size_t base = (size_t)t * 1024 + tid * 4;
    float4 v = *(const float4*)(h + base);
    for (int p = 0; p < nparts; ++p) {
        bf16x4 a = *(const bf16x4*)(parts + (size_t)p * 524288 + base);
        v.x += (float)a[0]; v.y += (float)a[1]; v.z += (float)a[2]; v.w += (float)a[3];
    }
    if (nparts) *(float4*)(h + base) = v;
    float ss = v.x * v.x + v.y * v.y + v.z * v.z + v.w * v.w;
#pragma unroll
    for (int m = 1; m < 64; m <<= 1) ss += __shfl_xor(ss, m);
    __shared__ float red[4];
    if ((tid & 63) == 0) red[tid >> 6] = ss;
    __syncthreads();
    float tot = (red[0] + red[1]) + (red[2] + red[3]);
    float sc = rsqrtf(tot * (1.0f / 1024.0f) + 1e-6f);
    float4 wv4 = *(const float4*)(w + tid * 4);
    bf16x4 o;
    o[0] = (bf16_t)(v.x * sc * wv4.x);
    o[1] = (bf16_t)(v.y * sc * wv4.y);
    o[2] = (bf16_t)(v.z * sc * wv4.z);
    o[3] = (bf16_t)(v.w * sc * wv4.w);
    *(bf16x4*)(ximg + aoff(t, tid * 4, 16)) = o;
}

// ---------------------------------------------------------------------------
__global__ __launch_bounds__(256) void k_finalize(
    const float* __restrict__ h, const bf16_t* __restrict__ parts,
    float* __restrict__ out)
{
    size_t base = ((size_t)blockIdx.x * 256 + threadIdx.x) * 4;
    float4 v = *(const float4*)(h + base);
#pragma unroll
    for (int p = 0; p < 4; ++p) {
        bf16x4 a = *(const bf16x4*)(parts + (size_t)p * 524288 + base);
        v.x += (float)a[0]; v.y += (float)a[1]; v.z += (float)a[2]; v.w += (float)a[3];
    }
    *(float4*)(out + base) = v;
}

// ---------------------------------------------------------------------------
// GEMM core: BM=64, BN=128, BK=64; 4 waves (2x2), 32x64 per wave.
// MODE 0: bf16 split-K partials. MODE 1: gu paired swiglu -> image. MODE 2: f16.
template <int NBN, int SPLITK, int MODE, int LDAK>
__device__ __forceinline__ void gemm_core(
    const char* __restrict__ Aimg, const char* __restrict__ Bimg,
    void* __restrict__ outp, char* smem, int f)
{
    const int steps = LDAK / SPLITK;
    int bm = f / (NBN * SPLITK);
    int r = f % (NBN * SPLITK);
    int s = r / NBN;
    int bn = r % NBN;
    int k0d = s * steps;

    int tid = threadIdx.x;
    int wv = tid >> 6, l = tid & 63, lg = l >> 4, lr = l & 15;
    int wr = wv >> 1, wc = wv & 1;

    f32x4 acc[2][4];
#pragma unroll
    for (int i = 0; i < 2; ++i)
#pragma unroll
        for (int j = 0; j < 4; ++j) { f32x4 z = {0.f, 0.f, 0.f, 0.f}; acc[i][j] = z; }

    auto stage = [&](int buf, int kt) {
        const char* ab = Aimg + ((size_t)(bm * LDAK + k0d + kt)) * 8192;
        const char* b0 = Bimg + ((size_t)((2 * bn) * LDAK + k0d + kt)) * 8192;
        const char* b1 = Bimg + ((size_t)((2 * bn + 1) * LDAK + k0d + kt)) * 8192;
        char* al = smem + buf * 24576;
        char* bl = al + 8192;
#pragma unroll
        for (int u = 0; u < 2; ++u) {
            int off = (wv * 2 + u) * 1024;
            gload16(ab + off + l * 16, al + off);
        }
#pragma unroll
        for (int u = 0; u < 4; ++u) {
            int off = (wv * 4 + u) * 1024;
            const char* src = (off < 8192) ? (b0 + off) : (b1 + off - 8192);
            gload16(src + l * 16, bl + off);
        }
    };
    auto compute = [&](int buf) {
        const char* as = smem + buf * 24576;
        const char* bs = as + 8192 + wc * 8192;
#pragma unroll
        for (int c = 0; c < 2; ++c) {
            int co = (c * 64 + lg * 16) ^ ((lr & 7) << 4);
            bf16x8 af[2], bf[4];
#pragma unroll
            for (int i = 0; i < 2; ++i)
                af[i] = *(const bf16x8*)(as + (wr * 32 + i * 16 + lr) * 128 + co);
#pragma unroll
            for (int j = 0; j < 4; ++j)
                bf[j] = *(const bf16x8*)(bs + (j * 16 + lr) * 128 + co);
#pragma unroll
            for (int i = 0; i < 2; ++i)
#pragma unroll
                for (int j = 0; j < 4; ++j)
                    acc[i][j] = __builtin_amdgcn_mfma_f32_16x16x32_bf16(
                        af[i], bf[j], acc[i][j], 0, 0, 0);
        }
    };

    stage(0, 0);
    __syncthreads();
    int buf = 0;
    for (int kt = 0; kt < steps; ++kt) {
        if (kt + 1 < steps) stage(buf ^ 1, kt + 1);
        compute(buf);
        __syncthreads();
        buf ^= 1;
    }

    if (MODE == 0) {
        bf16_t* P = (bf16_t*)outp + (size_t)s * 524288;
#pragma unroll
        for (int i = 0; i < 2; ++i)
#pragma unroll
            for (int j = 0; j < 4; ++j)
#pragma unroll
                for (int ii = 0; ii < 4; ++ii) {
                    int row = bm * 64 + wr * 32 + i * 16 + lg * 4 + ii;
                    int col = bn * 128 + wc * 64 + j * 16 + lr;
                    P[(size_t)row * 1024 + col] = (bf16_t)acc[i][j][ii];
                }
    } else if (MODE == 2) {
        f16_t* Q = (f16_t*)outp;
#pragma unroll
        for (int i = 0; i < 2; ++i)
#pragma unroll
            for (int j = 0; j < 4; ++j)
#pragma unroll
                for (int ii = 0; ii < 4; ++ii) {
                    int row = bm * 64 + wr * 32 + i * 16 + lg * 4 + ii;
                    int col = bn * 128 + wc * 64 + j * 16 + lr;
                    Q[(size_t)row * 4096 + col] = (f16_t)acc[i][j][ii];
                }
    } else {
        char* M = (char*)outp;
#pragma unroll
        for (int i = 0; i < 2; ++i)
#pragma unroll
            for (int jp = 0; jp < 2; ++jp)
#pragma unroll
                for (int ii = 0; ii < 4; ++ii) {
                    int row = bm * 64 + wr * 32 + i * 16 + lg * 4 + ii;
                    int col = (bn * 2 + wc) * 32 + jp * 16 + lr;
                    float gv = acc[i][2 * jp][ii];
                    float uv = acc[i][2 * jp + 1][ii];
                    float val = gv / (1.f + __expf(-gv)) * uv;
                    *(bf16_t*)(M + aoff(row, col, 48)) = (bf16_t)val;
                }
    }
}

__global__ __launch_bounds__(256) void g_qkv(const char* A, const char* B, f16_t* out)
{
    __shared__ __align__(128) char smem[49152];
    gemm_core<32, 1, 2, 16>(A, B, out, smem, blockIdx.x);
}
__global__ __launch_bounds__(256) void g_wo(const char* A, const char* B, bf16_t* parts)
{
    __shared__ __align__(128) char smem[49152];
    gemm_core<8, 4, 0, 32>(A, B, parts, smem, blockIdx.x);
}
__global__ __launch_bounds__(256) void g_gu(const char* A, const char* B, char* mimg)
{
    __shared__ __align__(128) char smem[49152];
    gemm_core<48, 1, 1, 16>(A, B, mimg, smem, blockIdx.x);
}
// wd GEMM + next-layer weight conv, merged
__global__ __launch_bounds__(256) void k_wdc(
    const char* A, const char* B, bf16_t* parts,
    const float* Wq, const float* Wk, const float* Wv, const float* Wo,
    const float* Wg, const float* Wu, const float* Wd,
    int lnext, char* imgnext)
{
    __shared__ __align__(128) char smem[49152];
    int b = blockIdx.x;
    if (b < 256) gemm_core<8, 4, 0, 48>(A, B, parts, smem, b);
    else conv_tile(b - 256, lnext, Wq, Wk, Wv, Wo, Wg, Wu, Wd, imgnext, smem);
}

// ---------------------------------------------------------------------------
// merged q/k RMSNorm+RoPE (blocks 0..3071) and V transpose (blocks 3072..3103)
__global__ __launch_bounds__(256) void k_qv(
    const f16_t* __restrict__ qkvh,
    const float* __restrict__ qw, const float* __restrict__ kw,
    const float* __restrict__ cosb, const float* __restrict__ sinb,
    f16_t* __restrict__ qf, f16_t* __restrict__ kf, f16_t* __restrict__ vT)
{
    int b = blockIdx.x;
    int tid = threadIdx.x;
    if (b < 3072) {
        int idx = b * 4 + (tid >> 6);
        int slot = idx % 24;
        int t = idx / 24;
        int d = tid & 63;
        bool isq = slot < 16;
        int col = isq ? slot * HD + d : 2048 + (slot - 16) * HD + d;
        const f16_t* row = qkvh + (size_t)t * 4096;
        float x1 = (float)row[col];
        float x2 = (float)row[col + 64];
        float ss = x1 * x1 + x2 * x2;
#pragma unroll
        for (int m = 1; m < 64; m <<= 1) ss += __shfl_xor(ss, m);
        float sc = rsqrtf(ss * (1.0f / 128.0f) + 1e-6f);
        float w1 = isq ? qw[d] : kw[d];
        float w2 = isq ? qw[d + 64] : kw[d + 64];
        float xn1 = x1 * sc * w1, xn2 = x2 * sc * w2;
        float o1 = xn1 * cosb[t * HD + d] - xn2 * sinb[t * HD + d];
        float o2 = xn2 * cosb[t * HD + d + 64] + xn1 * sinb[t * HD + d + 64];
        if (isq) {
            f16_t* o = qf + ((size_t)slot * SEQ + t) * HD;
            o[d] = (f16_t)o1; o[d + 64] = (f16_t)o2;
        } else {
            f16_t* o = kf + ((size_t)(slot - 16) * SEQ + t) * HD;
            o[d] = (f16_t)o1; o[d + 64] = (f16_t)o2;
        }
    } else {
        __shared__ f16_t tileS[128][136];
        int vb = b - 3072;
        int kvh = vb >> 2, tb = vb & 3;
#pragma unroll
        for (int it = 0; it < 8; ++it) {
            int r = it * 16 + (tid >> 4);
            int cs = tid & 15;
            f16x8 v = *(const f16x8*)(qkvh + (size_t)(tb * 128 + r) * 4096 + 3072 + kvh * HD + cs * 8);
            *(f16x8*)&tileS[r][cs * 8] = v;
        }
        __syncthreads();
#pragma unroll
        for (int it = 0; it < 8; ++it) {
            int dr = it * 16 + (tid >> 4);
            int seg = tid & 15;
            f16x8 o;
#pragma unroll
            for (int j = 0; j < 8; ++j) o[j] = tileS[seg * 8 + j][dr];
            *(f16x8*)(vT + ((size_t)kvh * HD + dr) * SEQ + tb * 128 + seg * 8) = o;
        }
    }
}

// ---------------------------------------------------------------------------
// causal flash attention -> attn-out image (tiled-swizzled bf16)
__global__ __launch_bounds__(128) void k_attn(
    const f16_t* __restrict__ qf, const f16_t* __restrict__ kf,
    const f16_t* __restrict__ vT, char* __restrict__ attimg)
{
    int h = blockIdx.x >> 4, qb = blockIdx.x & 15;
    int kvh = h >> 1;
    __shared__ f16_t Kt[64][136];
    __shared__ f16_t Vt[128][72];
    __shared__ f16_t Pl[2][16][72];
    int tid = threadIdx.x;
    int wv = tid >> 6, l = tid & 63, lg = l >> 4, lr = l & 15;
    int q0 = qb * 32;
    int qrow = q0 + wv * 16;

    f16x8 aq[4];
    const f16_t* qp = qf + ((size_t)h * SEQ + qrow + lr) * HD;
#pragma unroll
    for (int c = 0; c < 4; ++c) aq[c] = *(const f16x8*)(qp + c * 32 + lg * 8);

    f32x4 accv[8];
#pragma unroll
    for (int df = 0; df < 8; ++df) { f32x4 z = {0.f, 0.f, 0.f, 0.f}; accv[df] = z; }
    float mrun[4], lrun[4];
#pragma unroll
    for (int ii = 0; ii < 4; ++ii) { mrun[ii] = -3e38f; lrun[ii] = 0.f; }

    int ktiles = (q0 + 32 + 63) >> 6;
    for (int kt = 0; kt < ktiles; ++kt) {
        int kt0 = kt * 64;
        __syncthreads();
#pragma unroll
        for (int it = 0; it < 8; ++it) {
            int idx = it * 128 + tid;
            int r = idx >> 4, seg = idx & 15;
            *(int4*)&Kt[r][seg * 8] =
                *(const int4*)(kf + ((size_t)kvh * SEQ + kt0 + r) * HD + seg * 8);
        }
#pragma unroll
        for (int it = 0; it < 8; ++it) {
            int idx = it * 128 + tid;
            int r = idx >> 3, seg = idx & 7;
            *(int4*)&Vt[r][seg * 8] =
                *(const int4*)(vT + ((size_t)kvh * HD + r) * SEQ + kt0 + seg * 8);
        }
        __syncthreads();

        f32x4 s[4];
#pragma unroll
        for (int nf = 0; nf < 4; ++nf) {
            f32x4 a = {0.f, 0.f, 0.f, 0.f};
#pragma unroll
            for (int c = 0; c < 4; ++c) {
                f16x8 bk = *(const f16x8*)&Kt[nf * 16 + lr][c * 32 + lg * 8];
                a = __builtin_amdgcn_mfma_f32_16x16x32_f16(aq[c], bk, a, 0, 0, 0);
            }
            s[nf] = a;
        }
        const float scale = 0.08838834764831845f;
        float tmax[4] = {-3e38f, -3e38f, -3e38f, -3e38f};
#pragma unroll
        for (int nf = 0; nf < 4; ++nf) {
            int ktg = kt0 + nf * 16 + lr;
#pragma unroll
            for (int ii = 0; ii < 4; ++ii) {
                int qg = qrow + lg * 4 + ii;
                float vv = s[nf][ii] * scale;
                vv = (ktg <= qg) ? vv : -1e30f;
                s[nf][ii] = vv;
                tmax[ii] = fmaxf(tmax[ii], vv);
            }
        }
#pragma unroll
        for (int m = 1; m < 16; m <<= 1)
#pragma unroll
            for (int ii = 0; ii < 4; ++ii)
                tmax[ii] = fmaxf(tmax[ii], __shfl_xor(tmax[ii], m));
        float corr[4];
#pragma unroll
        for (int ii = 0; ii < 4; ++ii) {
            float mnew = fmaxf(mrun[ii], tmax[ii]);
            corr[ii] = __expf(mrun[ii] - mnew);
            mrun[ii] = mnew;
        }
        float tsum[4] = {0.f, 0.f, 0.f, 0.f};
#pragma unroll
        for (int nf = 0; nf < 4; ++nf)
#pragma unroll
            for (int ii = 0; ii < 4; ++ii) {
                float pp = __expf(s[nf][ii] - mrun[ii]);
                s[nf][ii] = pp;
                tsum[ii] += pp;
            }
#pragma unroll
        for (int m = 1; m < 16; m <<= 1)
#pragma unroll
            for (int ii = 0; ii < 4; ++ii) tsum[ii] += __shfl_xor(tsum[ii], m);
#pragma unroll
        for (int ii = 0; ii < 4; ++ii) lrun[ii] = lrun[ii] * corr[ii] + tsum[ii];
#pragma unroll
        for (int df = 0; df < 8; ++df)
#pragma unroll
            for (int ii = 0; ii < 4; ++ii) accv[df][ii] *= corr[ii];
#pragma unroll
        for (int nf = 0; nf < 4; ++nf)
#pragma unroll
            for (int ii = 0; ii < 4; ++ii)
                Pl[wv][lg * 4 + ii][nf * 16 + lr] = (f16_t)s[nf][ii];
        __syncthreads();
#pragma unroll
        for (int c = 0; c < 2; ++c) {
            f16x8 ap = *(const f16x8*)&Pl[wv][lr][c * 32 + lg * 8];
#pragma unroll
            for (int df = 0; df < 8; ++df) {
                f16x8 bv = *(const f16x8*)&Vt[df * 16 + lr][c * 32 + lg * 8];
                accv[df] = __builtin_amdgcn_mfma_f32_16x16x32_f16(ap, bv, accv[df], 0, 0, 0);
            }
        }
    }
#pragma unroll
    for (int df = 0; df < 8; ++df)
#pragma unroll
        for (int ii = 0; ii < 4; ++ii) {
            int qg = qrow + lg * 4 + ii;
            int col = h * HD + df * 16 + lr;
            *(bf16_t*)(attimg + aoff(qg, col, 32)) =
                (bf16_t)(accv[df][ii] / lrun[ii]);
        }
}

// ---------------------------------------------------------------------------
extern "C" void kernel_launch(void* const* d_in, const int* in_sizes, int n_in,
                              void* d_out, int out_size, void* d_ws, size_t ws_size,
                              hipStream_t stream)
{
    const float* hin  = (const float*)d_in[0];
    const float* cosb = (const float*)d_in[1];
    const float* sinb = (const float*)d_in[2];
    const float* Wq = (const float*)d_in[4];
    const float* Wk = (const float*)d_in[5];
    const float* Wv = (const float*)d_in[6];
    const float* Wo = (const float*)d_in[7];
    const float* Wg = (const float*)d_in[8];
    const float* Wu = (const float*)d_in[9];
    const float* Wd = (const float*)d_in[10];
    const float* Ln1 = (const float*)d_in[11];
    const float* Ln2 = (const float*)d_in[12];
    const float* Qn = (const float*)d_in[13];
    const float* Kn = (const float*)d_in[14];

    char* p = (char*)d_ws;
    auto alloc = [&](size_t bytes) { char* r = p; p += bytes; return r; };
    float*  h     = (float*)alloc(2097152);
    bf16_t* parts = (bf16_t*)alloc(4194304);      // 4 x 1MB bf16 partials
    char*   ximg  = alloc(1048576);
    char*   yimg  = alloc(1048576);
    char*   attimg= alloc(2097152);
    char*   mimg  = alloc(3145728);
    f16_t*  qkvh  = (f16_t*)alloc(4194304);
    f16_t*  qf    = (f16_t*)alloc(2097152);
    f16_t*  kf    = (f16_t*)alloc(1048576);
    f16_t*  vT    = (f16_t*)alloc(1048576);
    char*   imgA  = alloc(IMG_LAYER_BYTES);
    size_t fixed = (size_t)(imgA + IMG_LAYER_BYTES - (char*)d_ws);
    bool pp = ws_size >= fixed + IMG_LAYER_BYTES;
    char* imgB = pp ? alloc(IMG_LAYER_BYTES) : imgA;

    k_copy<<<512, 256, 0, stream>>>(hin, h);
    k_conv<<<3840, 256, 0, stream>>>(0, Wq, Wk, Wv, Wo, Wg, Wu, Wd, imgA);

    for (int l = 0; l < 28; ++l) {
        char* img  = (l & 1) ? imgB : imgA;
        char* imgn = (l & 1) ? imgA : imgB;

        k_rms<<<512, 256, 0, stream>>>(h, parts, l == 0 ? 0 : 4,
                                       Ln1 + (size_t)l * 1024, ximg);
        g_qkv<<<256, 256, 0, stream>>>(ximg, img + IMG_QKV, qkvh);
        k_qv<<<3104, 256, 0, stream>>>(qkvh, Qn + (size_t)l * 128,
                                       Kn + (size_t)l * 128, cosb, sinb,
                                       qf, kf, vT);
        k_attn<<<256, 128, 0, stream>>>(qf, kf, vT, attimg);
        g_wo<<<256, 256, 0, stream>>>(attimg, img + IMG_WO, parts);
        k_rms<<<512, 256, 0, stream>>>(h, parts, 4, Ln2 + (size_t)l * 1024, yimg);
        g_gu<<<384, 256, 0, stream>>>(yimg, img + IMG_GU, mimg);

        bool fuse = pp && (l < 27);
        k_wdc<<<fuse ? 4096 : 256, 256, 0, stream>>>(
            mimg, img + IMG_WD, parts, Wq, Wk, Wv, Wo, Wg, Wu, Wd,
            l + 1, imgn);
        if (!pp && l < 27)
            k_conv<<<3840, 256, 0, stream>>>(l + 1, Wq, Wk, Wv, Wo, Wg, Wu, Wd, imgA);
    }
    k_finalize<<<512, 256, 0, stream>>>(h, parts, (float*)d_out);
}

// Round 5
// 2353.639 us; speedup vs baseline: 1.8694x; 1.0909x over previous
//
#include <hip/hip_runtime.h>
#include <stdint.h>

// Qwen3 decoder, 28L, Q=512, D=1024, HQ=16, HKV=8, HD=128, DFF=3072.
// R5: counted-vmcnt 2-barrier GEMM K-loop (no vmcnt(0) drain), setprio around
// MFMA; qk-norm+rope+v-transpose fused into qkv GEMM epilogue (k_qv removed).

typedef __bf16 bf16_t;
typedef _Float16 f16_t;
typedef __bf16 bf16x8 __attribute__((ext_vector_type(8)));
typedef __bf16 bf16x4 __attribute__((ext_vector_type(4)));
typedef _Float16 f16x8 __attribute__((ext_vector_type(8)));
typedef float f32x4 __attribute__((ext_vector_type(4)));

#define SEQ 512
#define NHQ 16
#define NHKV 8
#define HD 128

#define IMG_QKV 0ull
#define IMG_WO  8388608ull
#define IMG_GU  12582912ull
#define IMG_WD  25165824ull
#define IMG_LAYER_BYTES 31457280ull

typedef const __attribute__((address_space(1))) uint32_t as1_u32;
typedef __attribute__((address_space(3))) uint32_t as3_u32;

__device__ __forceinline__ void gload16(const void* g, void* l) {
    __builtin_amdgcn_global_load_lds((as1_u32*)g, (as3_u32*)l, 16, 0, 0);
}

#define WAITV6 asm volatile("s_waitcnt vmcnt(6)" ::: "memory")
#define WAITV0 asm volatile("s_waitcnt vmcnt(0)" ::: "memory")

// byte offset into tiled-swizzled image (64x64 bf16 tiles, 8KB, [rowblk][kt])
__device__ __forceinline__ size_t aoff(int row, int col, int ldak) {
    return (((size_t)((row >> 6) * ldak + (col >> 6))) << 13) +
           ((size_t)(row & 63) << 7) +
           (size_t)((((col & 63) << 1)) ^ ((row & 7) << 4));
}

// ---------------------------------------------------------------------------
__global__ __launch_bounds__(256) void k_copy(const float* __restrict__ src,
                                              float* __restrict__ dst)
{
    size_t i = ((size_t)blockIdx.x * 256 + threadIdx.x) * 4;
    *(float4*)(dst + i) = *(const float4*)(src + i);
}

// ---------------------------------------------------------------------------
// weight tile convert: one 64x64 tile per block. Uniform [n][kt] tile order.
__device__ __forceinline__ void conv_tile(
    int b, int lay,
    const float* __restrict__ Wq, const float* __restrict__ Wk,
    const float* __restrict__ Wv, const float* __restrict__ Wo,
    const float* __restrict__ Wg, const float* __restrict__ Wu,
    const float* __restrict__ Wd, char* __restrict__ ib, void* smemv)
{
    const float* wq = Wq + (size_t)lay * 1024 * 2048;
    const float* wk = Wk + (size_t)lay * 1024 * 1024;
    const float* wv = Wv + (size_t)lay * 1024 * 1024;
    const float* wo = Wo + (size_t)lay * 2048 * 1024;
    const float* wg = Wg + (size_t)lay * 1024 * 3072;
    const float* wu = Wu + (size_t)lay * 1024 * 3072;
    const float* wd = Wd + (size_t)lay * 3072 * 1024;

    const float* src = nullptr;
    int ldbw = 0, n, kt, guMode = 0;
    size_t dstoff;
    if (b < 1024) {                      // qkv: 64 n x 16 kt
        n = b >> 4; kt = b & 15;
        int C0 = n * 64;
        if (C0 < 2048)      { src = wq + C0;          ldbw = 2048; }
        else if (C0 < 3072) { src = wk + (C0 - 2048); ldbw = 1024; }
        else                { src = wv + (C0 - 3072); ldbw = 1024; }
        src += (size_t)(kt * 64) * ldbw;
        dstoff = IMG_QKV + (size_t)b * 8192;
    } else if (b < 1536) {               // wo: 16 n x 32 kt
        int b2 = b - 1024; n = b2 >> 5; kt = b2 & 31;
        src = wo + (size_t)(kt * 64) * 1024 + n * 64; ldbw = 1024;
        dstoff = IMG_WO + (size_t)b2 * 8192;
    } else if (b < 3072) {               // gu: 96 n x 16 kt (g/u 16-interleave)
        int b3 = b - 1536; n = b3 >> 4; kt = b3 & 15;
        guMode = 1; ldbw = 3072;
        dstoff = IMG_GU + (size_t)b3 * 8192;
    } else {                             // wd: 16 n x 48 kt
        int b4 = b - 3072; n = b4 / 48; kt = b4 % 48;
        src = wd + (size_t)(kt * 64) * 1024 + n * 64; ldbw = 1024;
        dstoff = IMG_WD + (size_t)b4 * 8192;
    }

    float (*T)[68] = (float (*)[68])smemv;
    int tid = threadIdx.x;
    if (!guMode) {
#pragma unroll
        for (int it = 0; it < 4; ++it) {
            int idx = it * 256 + tid;
            int kk = idx >> 4, seg = idx & 15;
            *(float4*)&T[kk][seg * 4] = *(const float4*)(src + (size_t)kk * ldbw + seg * 4);
        }
    } else {
        const float* wg_ = wg + (size_t)(kt * 64) * 3072;
        const float* wu_ = wu + (size_t)(kt * 64) * 3072;
#pragma unroll
        for (int it = 0; it < 4; ++it) {
            int idx = it * 256 + tid;
            int kk = idx >> 4, seg = idx & 15;
            int nl = seg * 4;
            int colc = n * 32 + ((nl >> 5) & 1) * 16 + (nl & 15);
            const float* s2 = (((nl >> 4) & 1) ? wu_ : wg_) + (size_t)kk * 3072 + colc;
            *(float4*)&T[kk][nl] = *(const float4*)s2;
        }
    }
    __syncthreads();
    char* dst = ib + dstoff;
#pragma unroll
    for (int it = 0; it < 2; ++it) {
        int kg = tid & 7;
        int nrow = it * 32 + (tid >> 3);
        bf16x8 o;
#pragma unroll
        for (int j = 0; j < 8; ++j) o[j] = (bf16_t)T[kg * 8 + j][nrow];
        *(bf16x8*)(dst + nrow * 128 + ((kg * 16) ^ ((nrow & 7) << 4))) = o;
    }
}

__global__ __launch_bounds__(256) void k_conv(
    int lay,
    const float* __restrict__ Wq, const float* __restrict__ Wk,
    const float* __restrict__ Wv, const float* __restrict__ Wo,
    const float* __restrict__ Wg, const float* __restrict__ Wu,
    const float* __restrict__ Wd, char* __restrict__ img)
{
    __shared__ __align__(16) char smem[17408];
    conv_tile(blockIdx.x, lay, Wq, Wk, Wv, Wo, Wg, Wu, Wd, img, smem);
}

// ---------------------------------------------------------------------------
// residual(+4 bf16 splitK partials) + RMSNorm -> bf16 tiled-swizzled image
__global__ __launch_bounds__(256) void k_rms(
    float* __restrict__ h, const bf16_t* __restrict__ parts, int nparts,
    const float* __restrict__ w, char* __restrict__ ximg)
{
    int t = blockIdx.x, tid = threadIdx.x;
    size_t base = (size_t)t * 1024 + tid * 4;
    float4 v = *(const float4*)(h + base);
    for (int p = 0; p < nparts; ++p) {
        bf16x4 a = *(const bf16x4*)(parts + (size_t)p * 524288 + base);
        v.x += (float)a[0]; v.y += (float)a[1]; v.z += (float)a[2]; v.w += (float)a[3];
    }
    if (nparts) *(float4*)(h + base) = v;
    float ss = v.x * v.x + v.y * v.y + v.z * v.z + v.w * v.w;
#pragma unroll
    for (int m = 1; m < 64; m <<= 1) ss += __shfl_xor(ss, m);
    __shared__ float red[4];
    if ((tid & 63) == 0) red[tid >> 6] = ss;
    __syncthreads();
    float tot = (red[0] + red[1]) + (red[2] + red[3]);
    float sc = rsqrtf(tot * (1.0f / 1024.0f) + 1e-6f);
    float4 wv4 = *(const float4*)(w + tid * 4);
    bf16x4 o;
    o[0] = (bf16_t)(v.x * sc * wv4.x);
    o[1] = (bf16_t)(v.y * sc * wv4.y);
    o[2] = (bf16_t)(v.z * sc * wv4.z);
    o[3] = (bf16_t)(v.w * sc * wv4.w);
    *(bf16x4*)(ximg + aoff(t, tid * 4, 16)) = o;
}

// ---------------------------------------------------------------------------
__global__ __launch_bounds__(256) void k_finalize(
    const float* __restrict__ h, const bf16_t* __restrict__ parts,
    float* __restrict__ out)
{
    size_t base = ((size_t)blockIdx.x * 256 + threadIdx.x) * 4;
    float4 v = *(const float4*)(h + base);
#pragma unroll
    for (int p = 0; p < 4; ++p) {
        bf16x4 a = *(const bf16x4*)(parts + (size_t)p * 524288 + base);
        v.x += (float)a[0]; v.y += (float)a[1]; v.z += (float)a[2]; v.w += (float)a[3];
    }
    *(float4*)(out + base) = v;
}

// ---------------------------------------------------------------------------
// GEMM main loop: BM=64, BN=128, BK=64; 4 waves (2x2), 32x64 per wave.
// Counted-vmcnt pipeline: stage(t+1); vmcnt(6); barrier; compute(t); barrier.
template <int NBN, int SPLITK, int LDAK>
__device__ __forceinline__ void gemm_loop(
    const char* __restrict__ Aimg, const char* __restrict__ Bimg,
    char* smem, int f, f32x4 (&acc)[2][4], int& bmO, int& bnO, int& sO)
{
    const int steps = LDAK / SPLITK;
    int bm = f / (NBN * SPLITK);
    int r = f % (NBN * SPLITK);
    int s = r / NBN;
    int bn = r % NBN;
    int k0d = s * steps;
    bmO = bm; bnO = bn; sO = s;

    int tid = threadIdx.x;
    int wv = tid >> 6, l = tid & 63, lg = l >> 4, lr = l & 15;
    int wr = wv >> 1, wc = wv & 1;

#pragma unroll
    for (int i = 0; i < 2; ++i)
#pragma unroll
        for (int j = 0; j < 4; ++j) { f32x4 z = {0.f, 0.f, 0.f, 0.f}; acc[i][j] = z; }

    auto stage = [&](int buf, int kt) {
        const char* ab = Aimg + ((size_t)(bm * LDAK + k0d + kt)) * 8192;
        const char* b0 = Bimg + ((size_t)((2 * bn) * LDAK + k0d + kt)) * 8192;
        const char* b1 = Bimg + ((size_t)((2 * bn + 1) * LDAK + k0d + kt)) * 8192;
        char* al = smem + buf * 24576;
        char* bl = al + 8192;
#pragma unroll
        for (int u = 0; u < 2; ++u) {
            int off = (wv * 2 + u) * 1024;
            gload16(ab + off + l * 16, al + off);
        }
#pragma unroll
        for (int u = 0; u < 4; ++u) {
            int off = (wv * 4 + u) * 1024;
            const char* src = (off < 8192) ? (b0 + off) : (b1 + off - 8192);
            gload16(src + l * 16, bl + off);
        }
    };
    auto compute = [&](int buf) {
        const char* as = smem + buf * 24576;
        const char* bs = as + 8192 + wc * 8192;
        __builtin_amdgcn_s_setprio(1);
#pragma unroll
        for (int c = 0; c < 2; ++c) {
            int co = (c * 64 + lg * 16) ^ ((lr & 7) << 4);
            bf16x8 af[2], bf[4];
#pragma unroll
            for (int i = 0; i < 2; ++i)
                af[i] = *(const bf16x8*)(as + (wr * 32 + i * 16 + lr) * 128 + co);
#pragma unroll
            for (int j = 0; j < 4; ++j)
                bf[j] = *(const bf16x8*)(bs + (j * 16 + lr) * 128 + co);
#pragma unroll
            for (int i = 0; i < 2; ++i)
#pragma unroll
                for (int j = 0; j < 4; ++j)
                    acc[i][j] = __builtin_amdgcn_mfma_f32_16x16x32_bf16(
                        af[i], bf[j], acc[i][j], 0, 0, 0);
        }
        __builtin_amdgcn_s_setprio(0);
    };

    stage(0, 0);
    int buf = 0;
    for (int kt = 0; kt < steps; ++kt) {
        if (kt + 1 < steps) { stage(buf ^ 1, kt + 1); WAITV6; }
        else                { WAITV0; }
        __builtin_amdgcn_sched_barrier(0);
        __builtin_amdgcn_s_barrier();
        __builtin_amdgcn_sched_barrier(0);
        compute(buf);
        __builtin_amdgcn_s_barrier();
        buf ^= 1;
    }
}

// ---------------------------------------------------------------------------
// qkv GEMM with fused q/k rmsnorm+rope and v transpose (BN=128 = one head).
__global__ __launch_bounds__(256) void g_qkvf(
    const char* __restrict__ Aimg, const char* __restrict__ Bimg,
    const float* __restrict__ cosb, const float* __restrict__ sinb,
    const float* __restrict__ qw, const float* __restrict__ kw,
    f16_t* __restrict__ qf, f16_t* __restrict__ kf, f16_t* __restrict__ vT)
{
    __shared__ __align__(128) char smem[49152];
    f32x4 acc[2][4];
    int bm, bn, s;
    gemm_loop<32, 1, 16>(Aimg, Bimg, smem, blockIdx.x, acc, bm, bn, s);

    int tid = threadIdx.x;
    int wv = tid >> 6, l = tid & 63, lg = l >> 4, lr = l & 15;
    int wr = wv >> 1, wc = wv & 1;
    float (*X)[132] = (float (*)[132])smem;
#pragma unroll
    for (int i = 0; i < 2; ++i)
#pragma unroll
        for (int j = 0; j < 4; ++j)
#pragma unroll
            for (int ii = 0; ii < 4; ++ii)
                X[wr * 32 + i * 16 + lg * 4 + ii][wc * 64 + j * 16 + lr] = acc[i][j][ii];
    __syncthreads();

    int t0 = bm * 64;
    if (bn < 24) {
        bool isq = bn < 16;
        int slot = isq ? bn : bn - 16;
        const float* wn = isq ? qw : kw;
        int r = tid >> 2, part = tid & 3;
        float ss = 0.f;
#pragma unroll
        for (int c = 0; c < 32; ++c) { float v = X[r][part * 32 + c]; ss += v * v; }
        ss += __shfl_xor(ss, 1);
        ss += __shfl_xor(ss, 2);
        float sc = rsqrtf(ss * (1.0f / 128.0f) + 1e-6f);
        int t = t0 + r;
        int d0 = part * 16;
        float o1v[16], o2v[16];
#pragma unroll
        for (int c = 0; c < 16; ++c) {
            int d = d0 + c;
            float xv1 = X[r][d] * sc * wn[d];
            float xv2 = X[r][d + 64] * sc * wn[d + 64];
            o1v[c] = xv1 * cosb[t * HD + d] - xv2 * sinb[t * HD + d];
            o2v[c] = xv2 * cosb[t * HD + d + 64] + xv1 * sinb[t * HD + d + 64];
        }
        f16x8 w0, w1, w2, w3;
#pragma unroll
        for (int c = 0; c < 8; ++c) {
            w0[c] = (f16_t)o1v[c];     w1[c] = (f16_t)o1v[8 + c];
            w2[c] = (f16_t)o2v[c];     w3[c] = (f16_t)o2v[8 + c];
        }
        f16_t* o = (isq ? qf : kf) + ((size_t)slot * SEQ + t) * HD;
        *(f16x8*)(o + d0) = w0;
        *(f16x8*)(o + d0 + 8) = w1;
        *(f16x8*)(o + d0 + 64) = w2;
        *(f16x8*)(o + d0 + 72) = w3;
    } else {
        int kvh = bn - 24;
#pragma unroll
        for (int it = 0; it < 4; ++it) {
            int task = it * 256 + tid;
            int d = task >> 3, seg = task & 7;
            f16x8 o;
#pragma unroll
            for (int j = 0; j < 8; ++j) o[j] = (f16_t)X[seg * 8 + j][d];
            *(f16x8*)(vT + ((size_t)kvh * HD + d) * SEQ + t0 + seg * 8) = o;
        }
    }
}

// ---------------------------------------------------------------------------
// wo / wd GEMMs -> bf16 split-K partials
__global__ __launch_bounds__(256) void g_wo(const char* A, const char* B, bf16_t* parts)
{
    __shared__ __align__(128) char smem[49152];
    f32x4 acc[2][4];
    int bm, bn, s;
    gemm_loop<8, 4, 32>(A, B, smem, blockIdx.x, acc, bm, bn, s);
    int tid = threadIdx.x;
    int wv = tid >> 6, l = tid & 63, lg = l >> 4, lr = l & 15;
    int wr = wv >> 1, wc = wv & 1;
    bf16_t* P = parts + (size_t)s * 524288;
#pragma unroll
    for (int i = 0; i < 2; ++i)
#pragma unroll
        for (int j = 0; j < 4; ++j)
#pragma unroll
            for (int ii = 0; ii < 4; ++ii) {
                int row = bm * 64 + wr * 32 + i * 16 + lg * 4 + ii;
                int col = bn * 128 + wc * 64 + j * 16 + lr;
                P[(size_t)row * 1024 + col] = (bf16_t)acc[i][j][ii];
            }
}

__device__ __forceinline__ void wd_gemm(const char* A, const char* B,
                                        bf16_t* parts, char* smem, int f)
{
    f32x4 acc[2][4];
    int bm, bn, s;
    gemm_loop<8, 4, 48>(A, B, smem, f, acc, bm, bn, s);
    int tid = threadIdx.x;
    int wv = tid >> 6, l = tid & 63, lg = l >> 4, lr = l & 15;
    int wr = wv >> 1, wc = wv & 1;
    bf16_t* P = parts + (size_t)s * 524288;
#pragma unroll
    for (int i = 0; i < 2; ++i)
#pragma unroll
        for (int j = 0; j < 4; ++j)
#pragma unroll
            for (int ii = 0; ii < 4; ++ii) {
                int row = bm * 64 + wr * 32 + i * 16 + lg * 4 + ii;
                int col = bn * 128 + wc * 64 + j * 16 + lr;
                P[(size_t)row * 1024 + col] = (bf16_t)acc[i][j][ii];
            }
}

// gu GEMM with fused swiglu -> mimg
__global__ __launch_bounds__(256) void g_gu(const char* A, const char* B, char* mimg)
{
    __shared__ __align__(128) char smem[49152];
    f32x4 acc[2][4];
    int bm, bn, s;
    gemm_loop<48, 1, 16>(A, B, smem, blockIdx.x, acc, bm, bn, s);
    int tid = threadIdx.x;
    int wv = tid >> 6, l = tid & 63, lg = l >> 4, lr = l & 15;
    int wr = wv >> 1, wc = wv & 1;
#pragma unroll
    for (int i = 0; i < 2; ++i)
#pragma unroll
        for (int jp = 0; jp < 2; ++jp)
#pragma unroll
            for (int ii = 0; ii < 4; ++ii) {
                int row = bm * 64 + wr * 32 + i * 16 + lg * 4 + ii;
                int col = (bn * 2 + wc) * 32 + jp * 16 + lr;
                float gv = acc[i][2 * jp][ii];
                float uv = acc[i][2 * jp + 1][ii];
                float val = gv / (1.f + __expf(-gv)) * uv;
                *(bf16_t*)(mimg + aoff(row, col, 48)) = (bf16_t)val;
            }
}

// wd GEMM + next-layer weight conv, merged
__global__ __launch_bounds__(256) void k_wdc(
    const char* A, const char* B, bf16_t* parts,
    const float* Wq, const float* Wk, const float* Wv, const float* Wo,
    const float* Wg, const float* Wu, const float* Wd,
    int lnext, char* imgnext)
{
    __shared__ __align__(128) char smem[49152];
    int b = blockIdx.x;
    if (b < 256) wd_gemm(A, B, parts, smem, b);
    else conv_tile(b - 256, lnext, Wq, Wk, Wv, Wo, Wg, Wu, Wd, imgnext, smem);
}

// ---------------------------------------------------------------------------
// causal flash attention -> attn-out image (tiled-swizzled bf16)
__global__ __launch_bounds__(128) void k_attn(
    const f16_t* __restrict__ qf, const f16_t* __restrict__ kf,
    const f16_t* __restrict__ vT, char* __restrict__ attimg)
{
    int h = blockIdx.x >> 4, qb = blockIdx.x & 15;
    int kvh = h >> 1;
    __shared__ f16_t Kt[64][136];
    __shared__ f16_t Vt[128][72];
    __shared__ f16_t Pl[2][16][72];
    int tid = threadIdx.x;
    int wv = tid >> 6, l = tid & 63, lg = l >> 4, lr = l & 15;
    int q0 = qb * 32;
    int qrow = q0 + wv * 16;

    f16x8 aq[4];
    const f16_t* qp = qf + ((size_t)h * SEQ + qrow + lr) * HD;
#pragma unroll
    for (int c = 0; c < 4; ++c) aq[c] = *(const f16x8*)(qp + c * 32 + lg * 8);

    f32x4 accv[8];
#pragma unroll
    for (int df = 0; df < 8; ++df) { f32x4 z = {0.f, 0.f, 0.f, 0.f}; accv[df] = z; }
    float mrun[4], lrun[4];
#pragma unroll
    for (int ii = 0; ii < 4; ++ii) { mrun[ii] = -3e38f; lrun[ii] = 0.f; }

    int ktiles = (q0 + 32 + 63) >> 6;
    for (int kt = 0; kt < ktiles; ++kt) {
        int kt0 = kt * 64;
        __syncthreads();
#pragma unroll
        for (int it = 0; it < 8; ++it) {
            int idx = it * 128 + tid;
            int r = idx >> 4, seg = idx & 15;
            *(int4*)&Kt[r][seg * 8] =
                *(const int4*)(kf + ((size_t)kvh * SEQ + kt0 + r) * HD + seg * 8);
        }
#pragma unroll
        for (int it = 0; it < 8; ++it) {
            int idx = it * 128 + tid;
            int r = idx >> 3, seg = idx & 7;
            *(int4*)&Vt[r][seg * 8] =
                *(const int4*)(vT + ((size_t)kvh * HD + r) * SEQ + kt0 + seg * 8);
        }
        __syncthreads();

        f32x4 s[4];
#pragma unroll
        for (int nf = 0; nf < 4; ++nf) {
            f32x4 a = {0.f, 0.f, 0.f, 0.f};
#pragma unroll
            for (int c = 0; c < 4; ++c) {
                f16x8 bk = *(const f16x8*)&Kt[nf * 16 + lr][c * 32 + lg * 8];
                a = __builtin_amdgcn_mfma_f32_16x16x32_f16(aq[c], bk, a, 0, 0, 0);
            }
            s[nf] = a;
        }
        const float scale = 0.08838834764831845f;
        float tmax[4] = {-3e38f, -3e38f, -3e38f, -3e38f};
#pragma unroll
        for (int nf = 0; nf < 4; ++nf) {
            int ktg = kt0 + nf * 16 + lr;
#pragma unroll
            for (int ii = 0; ii < 4; ++ii) {
                int qg = qrow + lg * 4 + ii;
                float vv = s[nf][ii] * scale;
                vv = (ktg <= qg) ? vv : -1e30f;
                s[nf][ii] = vv;
                tmax[ii] = fmaxf(tmax[ii], vv);
            }
        }
#pragma unroll
        for (int m = 1; m < 16; m <<= 1)
#pragma unroll
            for (int ii = 0; ii < 4; ++ii)
                tmax[ii] = fmaxf(tmax[ii], __shfl_xor(tmax[ii], m));
        float corr[4];
#pragma unroll
        for (int ii = 0; ii < 4; ++ii) {
            float mnew = fmaxf(mrun[ii], tmax[ii]);
            corr[ii] = __expf(mrun[ii] - mnew);
            mrun[ii] = mnew;
        }
        float tsum[4] = {0.f, 0.f, 0.f, 0.f};
#pragma unroll
        for (int nf = 0; nf < 4; ++nf)
#pragma unroll
            for (int ii = 0; ii < 4; ++ii) {
                float pp = __expf(s[nf][ii] - mrun[ii]);
                s[nf][ii] = pp;
                tsum[ii] += pp;
            }
#pragma unroll
        for (int m = 1; m < 16; m <<= 1)
#pragma unroll
            for (int ii = 0; ii < 4; ++ii) tsum[ii] += __shfl_xor(tsum[ii], m);
#pragma unroll
        for (int ii = 0; ii < 4; ++ii) lrun[ii] = lrun[ii] * corr[ii] + tsum[ii];
#pragma unroll
        for (int df = 0; df < 8; ++df)
#pragma unroll
            for (int ii = 0; ii < 4; ++ii) accv[df][ii] *= corr[ii];
#pragma unroll
        for (int nf = 0; nf < 4; ++nf)
#pragma unroll
            for (int ii = 0; ii < 4; ++ii)
                Pl[wv][lg * 4 + ii][nf * 16 + lr] = (f16_t)s[nf][ii];
        __syncthreads();
#pragma unroll
        for (int c = 0; c < 2; ++c) {
            f16x8 ap = *(const f16x8*)&Pl[wv][lr][c * 32 + lg * 8];
#pragma unroll
            for (int df = 0; df < 8; ++df) {
                f16x8 bv = *(const f16x8*)&Vt[df * 16 + lr][c * 32 + lg * 8];
                accv[df] = __builtin_amdgcn_mfma_f32_16x16x32_f16(ap, bv, accv[df], 0, 0, 0);
            }
        }
    }
#pragma unroll
    for (int df = 0; df < 8; ++df)
#pragma unroll
        for (int ii = 0; ii < 4; ++ii) {
            int qg = qrow + lg * 4 + ii;
            int col = h * HD + df * 16 + lr;
            *(bf16_t*)(attimg + aoff(qg, col, 32)) =
                (bf16_t)(accv[df][ii] / lrun[ii]);
        }
}

// ---------------------------------------------------------------------------
extern "C" void kernel_launch(void* const* d_in, const int* in_sizes, int n_in,
                              void* d_out, int out_size, void* d_ws, size_t ws_size,
                              hipStream_t stream)
{
    const float* hin  = (const float*)d_in[0];
    const float* cosb = (const float*)d_in[1];
    const float* sinb = (const float*)d_in[2];
    const float* Wq = (const float*)d_in[4];
    const float* Wk = (const float*)d_in[5];
    const float* Wv = (const float*)d_in[6];
    const float* Wo = (const float*)d_in[7];
    const float* Wg = (const float*)d_in[8];
    const float* Wu = (const float*)d_in[9];
    const float* Wd = (const float*)d_in[10];
    const float* Ln1 = (const float*)d_in[11];
    const float* Ln2 = (const float*)d_in[12];
    const float* Qn = (const float*)d_in[13];
    const float* Kn = (const float*)d_in[14];

    char* p = (char*)d_ws;
    auto alloc = [&](size_t bytes) { char* r = p; p += bytes; return r; };
    float*  h     = (float*)alloc(2097152);
    bf16_t* parts = (bf16_t*)alloc(4194304);
    char*   ximg  = alloc(1048576);
    char*   yimg  = alloc(1048576);
    char*   attimg= alloc(2097152);
    char*   mimg  = alloc(3145728);
    f16_t*  qf    = (f16_t*)alloc(2097152);
    f16_t*  kf    = (f16_t*)alloc(1048576);
    f16_t*  vT    = (f16_t*)alloc(1048576);
    char*   imgA  = alloc(IMG_LAYER_BYTES);
    size_t fixed = (size_t)(imgA + IMG_LAYER_BYTES - (char*)d_ws);
    bool pp = ws_size >= fixed + IMG_LAYER_BYTES;
    char* imgB = pp ? alloc(IMG_LAYER_BYTES) : imgA;

    k_copy<<<512, 256, 0, stream>>>(hin, h);
    k_conv<<<3840, 256, 0, stream>>>(0, Wq, Wk, Wv, Wo, Wg, Wu, Wd, imgA);

    for (int l = 0; l < 28; ++l) {
        char* img  = (l & 1) ? imgB : imgA;
        char* imgn = (l & 1) ? imgA : imgB;

        k_rms<<<512, 256, 0, stream>>>(h, parts, l == 0 ? 0 : 4,
                                       Ln1 + (size_t)l * 1024, ximg);
        g_qkvf<<<256, 256, 0, stream>>>(ximg, img + IMG_QKV, cosb, sinb,
                                        Qn + (size_t)l * 128, Kn + (size_t)l * 128,
                                        qf, kf, vT);
        k_attn<<<256, 128, 0, stream>>>(qf, kf, vT, attimg);
        g_wo<<<256, 256, 0, stream>>>(attimg, img + IMG_WO, parts);
        k_rms<<<512, 256, 0, stream>>>(h, parts, 4, Ln2 + (size_t)l * 1024, yimg);
        g_gu<<<384, 256, 0, stream>>>(yimg, img + IMG_GU, mimg);

        bool fuse = pp && (l < 27);
        k_wdc<<<fuse ? 4096 : 256, 256, 0, stream>>>(
            mimg, img + IMG_WD, parts, Wq, Wk, Wv, Wo, Wg, Wu, Wd,
            l + 1, imgn);
        if (!pp && l < 27)
            k_conv<<<3840, 256, 0, stream>>>(l + 1, Wq, Wk, Wv, Wo, Wg, Wu, Wd, imgA);
    }
    k_finalize<<<512, 256, 0, stream>>>(h, parts, (float*)d_out);
}

// Round 6
// 2331.362 us; speedup vs baseline: 1.8872x; 1.0096x over previous
//
#include <hip/hip_runtime.h>
#include <stdint.h>

// Qwen3 decoder, 28L, Q=512, D=1024, HQ=16, HKV=8, HD=128, DFF=3072.
// R6: next-layer weight conv distributed across all 4 GEMM kernels (overlaps
// HBM weight stream with MFMA); attention heavy-tiles-first; counted-vmcnt
// 2-barrier GEMM K-loop; fused qkv epilogue (qknorm+rope+vT).

typedef __bf16 bf16_t;
typedef _Float16 f16_t;
typedef __bf16 bf16x8 __attribute__((ext_vector_type(8)));
typedef __bf16 bf16x4 __attribute__((ext_vector_type(4)));
typedef _Float16 f16x8 __attribute__((ext_vector_type(8)));
typedef float f32x4 __attribute__((ext_vector_type(4)));

#define SEQ 512
#define NHQ 16
#define NHKV 8
#define HD 128

#define IMG_QKV 0ull
#define IMG_WO  8388608ull
#define IMG_GU  12582912ull
#define IMG_WD  25165824ull
#define IMG_LAYER_BYTES 31457280ull

typedef const __attribute__((address_space(1))) uint32_t as1_u32;
typedef __attribute__((address_space(3))) uint32_t as3_u32;

__device__ __forceinline__ void gload16(const void* g, void* l) {
    __builtin_amdgcn_global_load_lds((as1_u32*)g, (as3_u32*)l, 16, 0, 0);
}

#define WAITV6 asm volatile("s_waitcnt vmcnt(6)" ::: "memory")
#define WAITV0 asm volatile("s_waitcnt vmcnt(0)" ::: "memory")

// byte offset into tiled-swizzled image (64x64 bf16 tiles, 8KB, [rowblk][kt])
__device__ __forceinline__ size_t aoff(int row, int col, int ldak) {
    return (((size_t)((row >> 6) * ldak + (col >> 6))) << 13) +
           ((size_t)(row & 63) << 7) +
           (size_t)((((col & 63) << 1)) ^ ((row & 7) << 4));
}

// ---------------------------------------------------------------------------
__global__ __launch_bounds__(256) void k_copy(const float* __restrict__ src,
                                              float* __restrict__ dst)
{
    size_t i = ((size_t)blockIdx.x * 256 + threadIdx.x) * 4;
    *(float4*)(dst + i) = *(const float4*)(src + i);
}

// ---------------------------------------------------------------------------
// weight tile convert: one 64x64 tile per block index b in [0,3840).
__device__ __forceinline__ void conv_tile(
    int b, int lay,
    const float* __restrict__ Wq, const float* __restrict__ Wk,
    const float* __restrict__ Wv, const float* __restrict__ Wo,
    const float* __restrict__ Wg, const float* __restrict__ Wu,
    const float* __restrict__ Wd, char* __restrict__ ib, void* smemv)
{
    const float* wq = Wq + (size_t)lay * 1024 * 2048;
    const float* wk = Wk + (size_t)lay * 1024 * 1024;
    const float* wv = Wv + (size_t)lay * 1024 * 1024;
    const float* wo = Wo + (size_t)lay * 2048 * 1024;
    const float* wg = Wg + (size_t)lay * 1024 * 3072;
    const float* wu = Wu + (size_t)lay * 1024 * 3072;
    const float* wd = Wd + (size_t)lay * 3072 * 1024;

    const float* src = nullptr;
    int ldbw = 0, n, kt, guMode = 0;
    size_t dstoff;
    if (b < 1024) {                      // qkv: 64 n x 16 kt
        n = b >> 4; kt = b & 15;
        int C0 = n * 64;
        if (C0 < 2048)      { src = wq + C0;          ldbw = 2048; }
        else if (C0 < 3072) { src = wk + (C0 - 2048); ldbw = 1024; }
        else                { src = wv + (C0 - 3072); ldbw = 1024; }
        src += (size_t)(kt * 64) * ldbw;
        dstoff = IMG_QKV + (size_t)b * 8192;
    } else if (b < 1536) {               // wo: 16 n x 32 kt
        int b2 = b - 1024; n = b2 >> 5; kt = b2 & 31;
        src = wo + (size_t)(kt * 64) * 1024 + n * 64; ldbw = 1024;
        dstoff = IMG_WO + (size_t)b2 * 8192;
    } else if (b < 3072) {               // gu: 96 n x 16 kt (g/u 16-interleave)
        int b3 = b - 1536; n = b3 >> 4; kt = b3 & 15;
        guMode = 1; ldbw = 3072;
        dstoff = IMG_GU + (size_t)b3 * 8192;
    } else {                             // wd: 16 n x 48 kt
        int b4 = b - 3072; n = b4 / 48; kt = b4 % 48;
        src = wd + (size_t)(kt * 64) * 1024 + n * 64; ldbw = 1024;
        dstoff = IMG_WD + (size_t)b4 * 8192;
    }

    float (*T)[68] = (float (*)[68])smemv;
    int tid = threadIdx.x;
    if (!guMode) {
#pragma unroll
        for (int it = 0; it < 4; ++it) {
            int idx = it * 256 + tid;
            int kk = idx >> 4, seg = idx & 15;
            *(float4*)&T[kk][seg * 4] = *(const float4*)(src + (size_t)kk * ldbw + seg * 4);
        }
    } else {
        const float* wg_ = wg + (size_t)(kt * 64) * 3072;
        const float* wu_ = wu + (size_t)(kt * 64) * 3072;
#pragma unroll
        for (int it = 0; it < 4; ++it) {
            int idx = it * 256 + tid;
            int kk = idx >> 4, seg = idx & 15;
            int nl = seg * 4;
            int colc = n * 32 + ((nl >> 5) & 1) * 16 + (nl & 15);
            const float* s2 = (((nl >> 4) & 1) ? wu_ : wg_) + (size_t)kk * 3072 + colc;
            *(float4*)&T[kk][nl] = *(const float4*)s2;
        }
    }
    __syncthreads();
    char* dst = ib + dstoff;
#pragma unroll
    for (int it = 0; it < 2; ++it) {
        int kg = tid & 7;
        int nrow = it * 32 + (tid >> 3);
        bf16x8 o;
#pragma unroll
        for (int j = 0; j < 8; ++j) o[j] = (bf16_t)T[kg * 8 + j][nrow];
        *(bf16x8*)(dst + nrow * 128 + ((kg * 16) ^ ((nrow & 7) << 4))) = o;
    }
}

__global__ __launch_bounds__(256) void k_conv(
    int lay,
    const float* __restrict__ Wq, const float* __restrict__ Wk,
    const float* __restrict__ Wv, const float* __restrict__ Wo,
    const float* __restrict__ Wg, const float* __restrict__ Wu,
    const float* __restrict__ Wd, char* __restrict__ img)
{
    __shared__ __align__(16) char smem[17408];
    conv_tile(blockIdx.x, lay, Wq, Wk, Wv, Wo, Wg, Wu, Wd, img, smem);
}

// ---------------------------------------------------------------------------
// residual(+4 bf16 splitK partials) + RMSNorm -> bf16 tiled-swizzled image
__global__ __launch_bounds__(256) void k_rms(
    float* __restrict__ h, const bf16_t* __restrict__ parts, int nparts,
    const float* __restrict__ w, char* __restrict__ ximg)
{
    int t = blockIdx.x, tid = threadIdx.x;
    size_t base = (size_t)t * 1024 + tid * 4;
    float4 v = *(const float4*)(h + base);
    for (int p = 0; p < nparts; ++p) {
        bf16x4 a = *(const bf16x4*)(parts + (size_t)p * 524288 + base);
        v.x += (float)a[0]; v.y += (float)a[1]; v.z += (float)a[2]; v.w += (float)a[3];
    }
    if (nparts) *(float4*)(h + base) = v;
    float ss = v.x * v.x + v.y * v.y + v.z * v.z + v.w * v.w;
#pragma unroll
    for (int m = 1; m < 64; m <<= 1) ss += __shfl_xor(ss, m);
    __shared__ float red[4];
    if ((tid & 63) == 0) red[tid >> 6] = ss;
    __syncthreads();
    float tot = (red[0] + red[1]) + (red[2] + red[3]);
    float sc = rsqrtf(tot * (1.0f / 1024.0f) + 1e-6f);
    float4 wv4 = *(const float4*)(w + tid * 4);
    bf16x4 o;
    o[0] = (bf16_t)(v.x * sc * wv4.x);
    o[1] = (bf16_t)(v.y * sc * wv4.y);
    o[2] = (bf16_t)(v.z * sc * wv4.z);
    o[3] = (bf16_t)(v.w * sc * wv4.w);
    *(bf16x4*)(ximg + aoff(t, tid * 4, 16)) = o;
}

// ---------------------------------------------------------------------------
__global__ __launch_bounds__(256) void k_finalize(
    const float* __restrict__ h, const bf16_t* __restrict__ parts,
    float* __restrict__ out)
{
    size_t base = ((size_t)blockIdx.x * 256 + threadIdx.x) * 4;
    float4 v = *(const float4*)(h + base);
#pragma unroll
    for (int p = 0; p < 4; ++p) {
        bf16x4 a = *(const bf16x4*)(parts + (size_t)p * 524288 + base);
        v.x += (float)a[0]; v.y += (float)a[1]; v.z += (float)a[2]; v.w += (float)a[3];
    }
    *(float4*)(out + base) = v;
}

// ---------------------------------------------------------------------------
// GEMM main loop: BM=64, BN=128, BK=64; 4 waves (2x2), 32x64 per wave.
// Counted-vmcnt pipeline: stage(t+1); vmcnt(6); barrier; compute(t); barrier.
template <int NBN, int SPLITK, int LDAK>
__device__ __forceinline__ void gemm_loop(
    const char* __restrict__ Aimg, const char* __restrict__ Bimg,
    char* smem, int f, f32x4 (&acc)[2][4], int& bmO, int& bnO, int& sO)
{
    const int steps = LDAK / SPLITK;
    int bm = f / (NBN * SPLITK);
    int r = f % (NBN * SPLITK);
    int s = r / NBN;
    int bn = r % NBN;
    int k0d = s * steps;
    bmO = bm; bnO = bn; sO = s;

    int tid = threadIdx.x;
    int wv = tid >> 6, l = tid & 63, lg = l >> 4, lr = l & 15;
    int wr = wv >> 1, wc = wv & 1;

#pragma unroll
    for (int i = 0; i < 2; ++i)
#pragma unroll
        for (int j = 0; j < 4; ++j) { f32x4 z = {0.f, 0.f, 0.f, 0.f}; acc[i][j] = z; }

    auto stage = [&](int buf, int kt) {
        const char* ab = Aimg + ((size_t)(bm * LDAK + k0d + kt)) * 8192;
        const char* b0 = Bimg + ((size_t)((2 * bn) * LDAK + k0d + kt)) * 8192;
        const char* b1 = Bimg + ((size_t)((2 * bn + 1) * LDAK + k0d + kt)) * 8192;
        char* al = smem + buf * 24576;
        char* bl = al + 8192;
#pragma unroll
        for (int u = 0; u < 2; ++u) {
            int off = (wv * 2 + u) * 1024;
            gload16(ab + off + l * 16, al + off);
        }
#pragma unroll
        for (int u = 0; u < 4; ++u) {
            int off = (wv * 4 + u) * 1024;
            const char* src = (off < 8192) ? (b0 + off) : (b1 + off - 8192);
            gload16(src + l * 16, bl + off);
        }
    };
    auto compute = [&](int buf) {
        const char* as = smem + buf * 24576;
        const char* bs = as + 8192 + wc * 8192;
        __builtin_amdgcn_s_setprio(1);
#pragma unroll
        for (int c = 0; c < 2; ++c) {
            int co = (c * 64 + lg * 16) ^ ((lr & 7) << 4);
            bf16x8 af[2], bf[4];
#pragma unroll
            for (int i = 0; i < 2; ++i)
                af[i] = *(const bf16x8*)(as + (wr * 32 + i * 16 + lr) * 128 + co);
#pragma unroll
            for (int j = 0; j < 4; ++j)
                bf[j] = *(const bf16x8*)(bs + (j * 16 + lr) * 128 + co);
#pragma unroll
            for (int i = 0; i < 2; ++i)
#pragma unroll
                for (int j = 0; j < 4; ++j)
                    acc[i][j] = __builtin_amdgcn_mfma_f32_16x16x32_bf16(
                        af[i], bf[j], acc[i][j], 0, 0, 0);
        }
        __builtin_amdgcn_s_setprio(0);
    };

    stage(0, 0);
    int buf = 0;
    for (int kt = 0; kt < steps; ++kt) {
        if (kt + 1 < steps) { stage(buf ^ 1, kt + 1); WAITV6; }
        else                { WAITV0; }
        __builtin_amdgcn_sched_barrier(0);
        __builtin_amdgcn_s_barrier();
        __builtin_amdgcn_sched_barrier(0);
        compute(buf);
        __builtin_amdgcn_s_barrier();
        buf ^= 1;
    }
}

// ---------------------------------------------------------------------------
// qkv GEMM with fused q/k rmsnorm+rope and v transpose (BN=128 = one head),
// plus distributed next-layer conv blocks.
__global__ __launch_bounds__(256) void g_qkvf(
    const char* __restrict__ Aimg, const char* __restrict__ Bimg,
    const float* __restrict__ cosb, const float* __restrict__ sinb,
    const float* __restrict__ qw, const float* __restrict__ kw,
    f16_t* __restrict__ qf, f16_t* __restrict__ kf, f16_t* __restrict__ vT,
    const float* Wq, const float* Wk, const float* Wv, const float* Wo,
    const float* Wg, const float* Wu, const float* Wd,
    int lnext, char* __restrict__ imgnext)
{
    __shared__ __align__(128) char smem[49152];
    if (blockIdx.x >= 256) {
        conv_tile(blockIdx.x - 256, lnext, Wq, Wk, Wv, Wo, Wg, Wu, Wd, imgnext, smem);
        return;
    }
    f32x4 acc[2][4];
    int bm, bn, s;
    gemm_loop<32, 1, 16>(Aimg, Bimg, smem, blockIdx.x, acc, bm, bn, s);

    int tid = threadIdx.x;
    int wv = tid >> 6, l = tid & 63, lg = l >> 4, lr = l & 15;
    int wr = wv >> 1, wc = wv & 1;
    float (*X)[132] = (float (*)[132])smem;
#pragma unroll
    for (int i = 0; i < 2; ++i)
#pragma unroll
        for (int j = 0; j < 4; ++j)
#pragma unroll
            for (int ii = 0; ii < 4; ++ii)
                X[wr * 32 + i * 16 + lg * 4 + ii][wc * 64 + j * 16 + lr] = acc[i][j][ii];
    __syncthreads();

    int t0 = bm * 64;
    if (bn < 24) {
        bool isq = bn < 16;
        int slot = isq ? bn : bn - 16;
        const float* wn = isq ? qw : kw;
        int r = tid >> 2, part = tid & 3;
        float ss = 0.f;
#pragma unroll
        for (int c = 0; c < 32; ++c) { float v = X[r][part * 32 + c]; ss += v * v; }
        ss += __shfl_xor(ss, 1);
        ss += __shfl_xor(ss, 2);
        float sc = rsqrtf(ss * (1.0f / 128.0f) + 1e-6f);
        int t = t0 + r;
        int d0 = part * 16;
        float o1v[16], o2v[16];
#pragma unroll
        for (int c = 0; c < 16; ++c) {
            int d = d0 + c;
            float xv1 = X[r][d] * sc * wn[d];
            float xv2 = X[r][d + 64] * sc * wn[d + 64];
            o1v[c] = xv1 * cosb[t * HD + d] - xv2 * sinb[t * HD + d];
            o2v[c] = xv2 * cosb[t * HD + d + 64] + xv1 * sinb[t * HD + d + 64];
        }
        f16x8 w0, w1, w2, w3;
#pragma unroll
        for (int c = 0; c < 8; ++c) {
            w0[c] = (f16_t)o1v[c];     w1[c] = (f16_t)o1v[8 + c];
            w2[c] = (f16_t)o2v[c];     w3[c] = (f16_t)o2v[8 + c];
        }
        f16_t* o = (isq ? qf : kf) + ((size_t)slot * SEQ + t) * HD;
        *(f16x8*)(o + d0) = w0;
        *(f16x8*)(o + d0 + 8) = w1;
        *(f16x8*)(o + d0 + 64) = w2;
        *(f16x8*)(o + d0 + 72) = w3;
    } else {
        int kvh = bn - 24;
#pragma unroll
        for (int it = 0; it < 4; ++it) {
            int task = it * 256 + tid;
            int d = task >> 3, seg = task & 7;
            f16x8 o;
#pragma unroll
            for (int j = 0; j < 8; ++j) o[j] = (f16_t)X[seg * 8 + j][d];
            *(f16x8*)(vT + ((size_t)kvh * HD + d) * SEQ + t0 + seg * 8) = o;
        }
    }
}

// ---------------------------------------------------------------------------
// wo GEMM -> bf16 split-K partials, plus distributed conv blocks
__global__ __launch_bounds__(256) void g_wo(
    const char* A, const char* B, bf16_t* parts,
    const float* Wq, const float* Wk, const float* Wv, const float* Wo,
    const float* Wg, const float* Wu, const float* Wd,
    int lnext, char* imgnext)
{
    __shared__ __align__(128) char smem[49152];
    if (blockIdx.x >= 256) {
        conv_tile(blockIdx.x - 256 + 960, lnext, Wq, Wk, Wv, Wo, Wg, Wu, Wd, imgnext, smem);
        return;
    }
    f32x4 acc[2][4];
    int bm, bn, s;
    gemm_loop<8, 4, 32>(A, B, smem, blockIdx.x, acc, bm, bn, s);
    int tid = threadIdx.x;
    int wv = tid >> 6, l = tid & 63, lg = l >> 4, lr = l & 15;
    int wr = wv >> 1, wc = wv & 1;
    bf16_t* P = parts + (size_t)s * 524288;
#pragma unroll
    for (int i = 0; i < 2; ++i)
#pragma unroll
        for (int j = 0; j < 4; ++j)
#pragma unroll
            for (int ii = 0; ii < 4; ++ii) {
                int row = bm * 64 + wr * 32 + i * 16 + lg * 4 + ii;
                int col = bn * 128 + wc * 64 + j * 16 + lr;
                P[(size_t)row * 1024 + col] = (bf16_t)acc[i][j][ii];
            }
}

// gu GEMM with fused swiglu -> mimg, plus distributed conv blocks
__global__ __launch_bounds__(256) void g_gu(
    const char* A, const char* B, char* mimg,
    const float* Wq, const float* Wk, const float* Wv, const float* Wo,
    const float* Wg, const float* Wu, const float* Wd,
    int lnext, char* imgnext)
{
    __shared__ __align__(128) char smem[49152];
    if (blockIdx.x >= 384) {
        conv_tile(blockIdx.x - 384 + 1920, lnext, Wq, Wk, Wv, Wo, Wg, Wu, Wd, imgnext, smem);
        return;
    }
    f32x4 acc[2][4];
    int bm, bn, s;
    gemm_loop<48, 1, 16>(A, B, smem, blockIdx.x, acc, bm, bn, s);
    int tid = threadIdx.x;
    int wv = tid >> 6, l = tid & 63, lg = l >> 4, lr = l & 15;
    int wr = wv >> 1, wc = wv & 1;
#pragma unroll
    for (int i = 0; i < 2; ++i)
#pragma unroll
        for (int jp = 0; jp < 2; ++jp)
#pragma unroll
            for (int ii = 0; ii < 4; ++ii) {
                int row = bm * 64 + wr * 32 + i * 16 + lg * 4 + ii;
                int col = (bn * 2 + wc) * 32 + jp * 16 + lr;
                float gv = acc[i][2 * jp][ii];
                float uv = acc[i][2 * jp + 1][ii];
                float val = gv / (1.f + __expf(-gv)) * uv;
                *(bf16_t*)(mimg + aoff(row, col, 48)) = (bf16_t)val;
            }
}

// wd GEMM + final conv chunk
__global__ __launch_bounds__(256) void k_wdc(
    const char* A, const char* B, bf16_t* parts,
    const float* Wq, const float* Wk, const float* Wv, const float* Wo,
    const float* Wg, const float* Wu, const float* Wd,
    int lnext, char* imgnext)
{
    __shared__ __align__(128) char smem[49152];
    int b = blockIdx.x;
    if (b >= 256) {
        conv_tile(b - 256 + 2880, lnext, Wq, Wk, Wv, Wo, Wg, Wu, Wd, imgnext, smem);
        return;
    }
    f32x4 acc[2][4];
    int bm, bn, s;
    gemm_loop<8, 4, 48>(A, B, smem, b, acc, bm, bn, s);
    int tid = threadIdx.x;
    int wv = tid >> 6, l = tid & 63, lg = l >> 4, lr = l & 15;
    int wr = wv >> 1, wc = wv & 1;
    bf16_t* P = parts + (size_t)s * 524288;
#pragma unroll
    for (int i = 0; i < 2; ++i)
#pragma unroll
        for (int j = 0; j < 4; ++j)
#pragma unroll
            for (int ii = 0; ii < 4; ++ii) {
                int row = bm * 64 + wr * 32 + i * 16 + lg * 4 + ii;
                int col = bn * 128 + wc * 64 + j * 16 + lr;
                P[(size_t)row * 1024 + col] = (bf16_t)acc[i][j][ii];
            }
}

// ---------------------------------------------------------------------------
// causal flash attention -> attn-out image; heavy q-tiles launched first.
__global__ __launch_bounds__(128) void k_attn(
    const f16_t* __restrict__ qf, const f16_t* __restrict__ kf,
    const f16_t* __restrict__ vT, char* __restrict__ attimg)
{
    int h = blockIdx.x >> 4, qb = 15 - (blockIdx.x & 15);
    int kvh = h >> 1;
    __shared__ f16_t Kt[64][136];
    __shared__ f16_t Vt[128][72];
    __shared__ f16_t Pl[2][16][72];
    int tid = threadIdx.x;
    int wv = tid >> 6, l = tid & 63, lg = l >> 4, lr = l & 15;
    int q0 = qb * 32;
    int qrow = q0 + wv * 16;

    f16x8 aq[4];
    const f16_t* qp = qf + ((size_t)h * SEQ + qrow + lr) * HD;
#pragma unroll
    for (int c = 0; c < 4; ++c) aq[c] = *(const f16x8*)(qp + c * 32 + lg * 8);

    f32x4 accv[8];
#pragma unroll
    for (int df = 0; df < 8; ++df) { f32x4 z = {0.f, 0.f, 0.f, 0.f}; accv[df] = z; }
    float mrun[4], lrun[4];
#pragma unroll
    for (int ii = 0; ii < 4; ++ii) { mrun[ii] = -3e38f; lrun[ii] = 0.f; }

    int ktiles = (q0 + 32 + 63) >> 6;
    for (int kt = 0; kt < ktiles; ++kt) {
        int kt0 = kt * 64;
        __syncthreads();
#pragma unroll
        for (int it = 0; it < 8; ++it) {
            int idx = it * 128 + tid;
            int r = idx >> 4, seg = idx & 15;
            *(int4*)&Kt[r][seg * 8] =
                *(const int4*)(kf + ((size_t)kvh * SEQ + kt0 + r) * HD + seg * 8);
        }
#pragma unroll
        for (int it = 0; it < 8; ++it) {
            int idx = it * 128 + tid;
            int r = idx >> 3, seg = idx & 7;
            *(int4*)&Vt[r][seg * 8] =
                *(const int4*)(vT + ((size_t)kvh * HD + r) * SEQ + kt0 + seg * 8);
        }
        __syncthreads();

        f32x4 s[4];
#pragma unroll
        for (int nf = 0; nf < 4; ++nf) {
            f32x4 a = {0.f, 0.f, 0.f, 0.f};
#pragma unroll
            for (int c = 0; c < 4; ++c) {
                f16x8 bk = *(const f16x8*)&Kt[nf * 16 + lr][c * 32 + lg * 8];
                a = __builtin_amdgcn_mfma_f32_16x16x32_f16(aq[c], bk, a, 0, 0, 0);
            }
            s[nf] = a;
        }
        const float scale = 0.08838834764831845f;
        float tmax[4] = {-3e38f, -3e38f, -3e38f, -3e38f};
#pragma unroll
        for (int nf = 0; nf < 4; ++nf) {
            int ktg = kt0 + nf * 16 + lr;
#pragma unroll
            for (int ii = 0; ii < 4; ++ii) {
                int qg = qrow + lg * 4 + ii;
                float vv = s[nf][ii] * scale;
                vv = (ktg <= qg) ? vv : -1e30f;
                s[nf][ii] = vv;
                tmax[ii] = fmaxf(tmax[ii], vv);
            }
        }
#pragma unroll
        for (int m = 1; m < 16; m <<= 1)
#pragma unroll
            for (int ii = 0; ii < 4; ++ii)
                tmax[ii] = fmaxf(tmax[ii], __shfl_xor(tmax[ii], m));
        float corr[4];
#pragma unroll
        for (int ii = 0; ii < 4; ++ii) {
            float mnew = fmaxf(mrun[ii], tmax[ii]);
            corr[ii] = __expf(mrun[ii] - mnew);
            mrun[ii] = mnew;
        }
        float tsum[4] = {0.f, 0.f, 0.f, 0.f};
#pragma unroll
        for (int nf = 0; nf < 4; ++nf)
#pragma unroll
            for (int ii = 0; ii < 4; ++ii) {
                float pp = __expf(s[nf][ii] - mrun[ii]);
                s[nf][ii] = pp;
                tsum[ii] += pp;
            }
#pragma unroll
        for (int m = 1; m < 16; m <<= 1)
#pragma unroll
            for (int ii = 0; ii < 4; ++ii) tsum[ii] += __shfl_xor(tsum[ii], m);
#pragma unroll
        for (int ii = 0; ii < 4; ++ii) lrun[ii] = lrun[ii] * corr[ii] + tsum[ii];
#pragma unroll
        for (int df = 0; df < 8; ++df)
#pragma unroll
            for (int ii = 0; ii < 4; ++ii) accv[df][ii] *= corr[ii];
#pragma unroll
        for (int nf = 0; nf < 4; ++nf)
#pragma unroll
            for (int ii = 0; ii < 4; ++ii)
                Pl[wv][lg * 4 + ii][nf * 16 + lr] = (f16_t)s[nf][ii];
        __syncthreads();
#pragma unroll
        for (int c = 0; c < 2; ++c) {
            f16x8 ap = *(const f16x8*)&Pl[wv][lr][c * 32 + lg * 8];
#pragma unroll
            for (int df = 0; df < 8; ++df) {
                f16x8 bv = *(const f16x8*)&Vt[df * 16 + lr][c * 32 + lg * 8];
                accv[df] = __builtin_amdgcn_mfma_f32_16x16x32_f16(ap, bv, accv[df], 0, 0, 0);
            }
        }
    }
#pragma unroll
    for (int df = 0; df < 8; ++df)
#pragma unroll
        for (int ii = 0; ii < 4; ++ii) {
            int qg = qrow + lg * 4 + ii;
            int col = h * HD + df * 16 + lr;
            *(bf16_t*)(attimg + aoff(qg, col, 32)) =
                (bf16_t)(accv[df][ii] / lrun[ii]);
        }
}

// ---------------------------------------------------------------------------
extern "C" void kernel_launch(void* const* d_in, const int* in_sizes, int n_in,
                              void* d_out, int out_size, void* d_ws, size_t ws_size,
                              hipStream_t stream)
{
    const float* hin  = (const float*)d_in[0];
    const float* cosb = (const float*)d_in[1];
    const float* sinb = (const float*)d_in[2];
    const float* Wq = (const float*)d_in[4];
    const float* Wk = (const float*)d_in[5];
    const float* Wv = (const float*)d_in[6];
    const float* Wo = (const float*)d_in[7];
    const float* Wg = (const float*)d_in[8];
    const float* Wu = (const float*)d_in[9];
    const float* Wd = (const float*)d_in[10];
    const float* Ln1 = (const float*)d_in[11];
    const float* Ln2 = (const float*)d_in[12];
    const float* Qn = (const float*)d_in[13];
    const float* Kn = (const float*)d_in[14];

    char* p = (char*)d_ws;
    auto alloc = [&](size_t bytes) { char* r = p; p += bytes; return r; };
    float*  h     = (float*)alloc(2097152);
    bf16_t* parts = (bf16_t*)alloc(4194304);
    char*   ximg  = alloc(1048576);
    char*   yimg  = alloc(1048576);
    char*   attimg= alloc(2097152);
    char*   mimg  = alloc(3145728);
    f16_t*  qf    = (f16_t*)alloc(2097152);
    f16_t*  kf    = (f16_t*)alloc(1048576);
    f16_t*  vT    = (f16_t*)alloc(1048576);
    char*   imgA  = alloc(IMG_LAYER_BYTES);
    size_t fixed = (size_t)(imgA + IMG_LAYER_BYTES - (char*)d_ws);
    bool pp = ws_size >= fixed + IMG_LAYER_BYTES;
    char* imgB = pp ? alloc(IMG_LAYER_BYTES) : imgA;

    k_copy<<<512, 256, 0, stream>>>(hin, h);
    k_conv<<<3840, 256, 0, stream>>>(0, Wq, Wk, Wv, Wo, Wg, Wu, Wd, imgA);

    for (int l = 0; l < 28; ++l) {
        char* img  = (l & 1) ? imgB : imgA;
        char* imgn = (l & 1) ? imgA : imgB;
        bool cv = pp && (l < 27);
        int ln = l + 1;

        k_rms<<<512, 256, 0, stream>>>(h, parts, l == 0 ? 0 : 4,
                                       Ln1 + (size_t)l * 1024, ximg);
        g_qkvf<<<cv ? 1216 : 256, 256, 0, stream>>>(
            ximg, img + IMG_QKV, cosb, sinb,
            Qn + (size_t)l * 128, Kn + (size_t)l * 128, qf, kf, vT,
            Wq, Wk, Wv, Wo, Wg, Wu, Wd, ln, imgn);
        k_attn<<<256, 128, 0, stream>>>(qf, kf, vT, attimg);
        g_wo<<<cv ? 1216 : 256, 256, 0, stream>>>(
            attimg, img + IMG_WO, parts,
            Wq, Wk, Wv, Wo, Wg, Wu, Wd, ln, imgn);
        k_rms<<<512, 256, 0, stream>>>(h, parts, 4, Ln2 + (size_t)l * 1024, yimg);
        g_gu<<<cv ? 1536 : 384, 256, 0, stream>>>(
            yimg, img + IMG_GU, mimg,
            Wq, Wk, Wv, Wo, Wg, Wu, Wd, ln, imgn);
        k_wdc<<<cv ? 1216 : 256, 256, 0, stream>>>(
            mimg, img + IMG_WD, parts,
            Wq, Wk, Wv, Wo, Wg, Wu, Wd, ln, imgn);
        if (!pp && l < 27)
            k_conv<<<3840, 256, 0, stream>>>(ln, Wq, Wk, Wv, Wo, Wg, Wu, Wd, imgA);
    }
    k_finalize<<<512, 256, 0, stream>>>(h, parts, (float*)d_out);
}